// Round 12
// baseline (19738.609 us; speedup 1.0000x reference)
//
#include <hip/hip_runtime.h>
#include <hip/hip_bf16.h>
#include <cfloat>

// Problem constants
#define NROWS 16384
#define INDIM 2048
#define DIMV  1024
#define NCODE 8192

typedef __attribute__((ext_vector_type(8))) short short8v;
typedef __attribute__((ext_vector_type(4))) float f32x4;

__device__ inline float clip10(float x) { return fminf(fmaxf(x, -10.f), 10.f); }

__device__ inline unsigned short f2bf(float x) {
  __hip_bfloat16 h = __float2bfloat16(x);  // RNE
  return *reinterpret_cast<unsigned short*>(&h);
}

__device__ inline float block_sum256(float v, float* sm) {
#pragma unroll
  for (int off = 32; off > 0; off >>= 1) v += __shfl_down(v, off, 64);
  int lane = threadIdx.x & 63, w = threadIdx.x >> 6;
  if (lane == 0) sm[w] = v;
  __syncthreads();
  float r = 0.f;
  if (threadIdx.x == 0) r = sm[0] + sm[1] + sm[2] + sm[3];
  return r;  // valid on thread 0 only
}

__global__ void zero_kernel(float* __restrict__ p, int n) {
  int i = blockIdx.x * 256 + threadIdx.x;
  if (i < n) p[i] = 0.f;
}

// OpenBLAS level3 K-panel boundaries (GEMM_Q=384, halving rule):
//   K=2048 -> 384,384,384,384,256,256 ; K=1024 -> 384,320,320
template <int KSEL>
__device__ inline bool kfold(int kend) {
  if (KSEL == 0)
    return kend == 384 || kend == 768 || kend == 1152 || kend == 1536 || kend == 1792 ||
           kend == 2048;
  return kend == 384 || kend == 704 || kend == 1024;
}

// ============== np-faithful fp32 GEMM: C = op(A)@B + bias ==================
// Sequential-k FMA chain per element, folded at OpenBLAS K-panel boundaries.
// 64x64 tile, BK=32, 256 threads, 4x4 per thread. (round-5 proven, unchanged)
template <int KSEL, bool CLIP>
__global__ __launch_bounds__(256) void gemm_np(const float* __restrict__ A,
                                               const float* __restrict__ B,
                                               const float* __restrict__ bias,
                                               float* __restrict__ C, int M, int N, int K) {
  __shared__ float As[32][68];  // [k][m]
  __shared__ float Bs[32][68];  // [k][n]
  const int tid = threadIdx.x;
  const int tx = tid & 15, ty = tid >> 4;
  const int row0 = blockIdx.y * 64;
  const int col0 = blockIdx.x * 64;
  float cur[4][4], tot[4][4];
#pragma unroll
  for (int i = 0; i < 4; ++i)
#pragma unroll
    for (int j = 0; j < 4; ++j) { cur[i][j] = 0.f; tot[i][j] = 0.f; }

  for (int k0 = 0; k0 < K; k0 += 32) {
#pragma unroll
    for (int l = 0; l < 2; ++l) {
      int s = tid + 256 * l;
      int r = s >> 3;
      int kq = (s & 7) << 2;
      float4 v = *reinterpret_cast<const float4*>(&A[(size_t)(row0 + r) * K + k0 + kq]);
      if (CLIP) { v.x = clip10(v.x); v.y = clip10(v.y); v.z = clip10(v.z); v.w = clip10(v.w); }
      As[kq + 0][r] = v.x; As[kq + 1][r] = v.y; As[kq + 2][r] = v.z; As[kq + 3][r] = v.w;
    }
#pragma unroll
    for (int l = 0; l < 2; ++l) {
      int s = tid + 256 * l;
      int kr = s >> 4;
      int c4 = (s & 15) << 2;
      *reinterpret_cast<float4*>(&Bs[kr][c4]) =
          *reinterpret_cast<const float4*>(&B[(size_t)(k0 + kr) * N + col0 + c4]);
    }
    __syncthreads();
#pragma unroll
    for (int kk = 0; kk < 32; ++kk) {  // k strictly ascending
      float4 a = *reinterpret_cast<const float4*>(&As[kk][ty * 4]);
      float4 b = *reinterpret_cast<const float4*>(&Bs[kk][tx * 4]);
      float da[4] = {a.x, a.y, a.z, a.w};
      float db[4] = {b.x, b.y, b.z, b.w};
#pragma unroll
      for (int i = 0; i < 4; ++i)
#pragma unroll
        for (int j = 0; j < 4; ++j) cur[i][j] = fmaf(da[i], db[j], cur[i][j]);
    }
    __syncthreads();
    if (kfold<KSEL>(k0 + 32)) {
#pragma unroll
      for (int i = 0; i < 4; ++i)
#pragma unroll
        for (int j = 0; j < 4; ++j) { tot[i][j] = __fadd_rn(tot[i][j], cur[i][j]); cur[i][j] = 0.f; }
    }
  }
#pragma unroll
  for (int i = 0; i < 4; ++i) {
    int row = row0 + ty * 4 + i;
#pragma unroll
    for (int j = 0; j < 4; ++j) {
      int col = col0 + tx * 4 + j;
      C[(size_t)row * N + col] = __fadd_rn(tot[i][j], bias[col]);
    }
  }
}

// ===== numpy pairwise row-sum of squares (AVX-512 base-case emulation) ======
__global__ __launch_bounds__(256) void rowsq_np(const float* __restrict__ X, int nrows,
                                                float* __restrict__ out) {
  int row = blockIdx.x * 256 + threadIdx.x;
  if (row >= nrows) return;
  const float* rp = X + (size_t)row * 1024;
  float Bres[8];
#pragma unroll
  for (int blk = 0; blk < 8; ++blk) {
    const float* p = rp + blk * 128;
    float x[16];
#pragma unroll
    for (int L = 0; L < 16; ++L) {
      float m0 = __fmul_rn(p[L], p[L]);
      float m1 = __fmul_rn(p[64 + L], p[64 + L]);
      float r0 = __fadd_rn(m0, m1);
      float m2 = __fmul_rn(p[16 + L], p[16 + L]);
      float m3 = __fmul_rn(p[80 + L], p[80 + L]);
      float r1 = __fadd_rn(m2, m3);
      float m4 = __fmul_rn(p[32 + L], p[32 + L]);
      float m5 = __fmul_rn(p[96 + L], p[96 + L]);
      float r2 = __fadd_rn(m4, m5);
      float m6 = __fmul_rn(p[48 + L], p[48 + L]);
      float m7 = __fmul_rn(p[112 + L], p[112 + L]);
      float r3 = __fadd_rn(m6, m7);
      x[L] = __fadd_rn(__fadd_rn(r0, r1), __fadd_rn(r2, r3));
    }
    float z[4];
#pragma unroll
    for (int i = 0; i < 4; ++i)
      z[i] = __fadd_rn(__fadd_rn(x[i], x[i + 8]), __fadd_rn(x[i + 4], x[i + 12]));
    Bres[blk] = __fadd_rn(__fadd_rn(z[0], z[2]), __fadd_rn(z[1], z[3]));
  }
  float s01 = __fadd_rn(Bres[0], Bres[1]);
  float s23 = __fadd_rn(Bres[2], Bres[3]);
  float s45 = __fadd_rn(Bres[4], Bres[5]);
  float s67 = __fadd_rn(Bres[6], Bres[7]);
  out[row] = __fadd_rn(__fadd_rn(s01, s23), __fadd_rn(s45, s67));
}

// ---------------- fp32 -> bf16 (RNE) conversion ----------------
__global__ __launch_bounds__(256) void tobf16_kernel(const float* __restrict__ x,
                                                     unsigned short* __restrict__ y, int n4) {
  int i = blockIdx.x * 256 + threadIdx.x;
  if (i >= n4) return;
  float4 v = *reinterpret_cast<const float4*>(x + (size_t)i * 4);
  ushort4 o;
  o.x = f2bf(v.x); o.y = f2bf(v.y); o.z = f2bf(v.z); o.w = f2bf(v.w);
  *reinterpret_cast<ushort4*>(y + (size_t)i * 4) = o;
}

// ====== MFMA bf16 filter pass: per-row min of S' = -2*(zh.ch) + c2 ==========
// over each 64-code group. Tile 64 rows x 64 codes, 4 waves, each wave owns
// 16 rows x 64 codes as 4 16x16 MFMA subtiles; K-loop 1024 in steps of 32
// (one mfma_f32_16x16x32_bf16 per subtile per step).
// Fragment layouts (guide §3, m89/m91 HW-verified): A row = lane&15,
// k-slice = (lane>>4)*8; B col = lane&15 (same k mapping -> any shared k
// permutation cancels). C/D: col = lane&15, row = (lane>>4)*4 + reg.
__global__ __launch_bounds__(256) void mfma_filter(const unsigned short* __restrict__ zh,
                                                   const unsigned short* __restrict__ ch,
                                                   const float* __restrict__ c2,
                                                   float* __restrict__ pv2) {
  __shared__ unsigned short As[64 * 40];  // stride 40 bf16 (80B): uniform bank quads
  __shared__ unsigned short Bs[64 * 40];
  const int tid = threadIdx.x;
  const int w = tid >> 6, l = tid & 63;
  const int row0 = blockIdx.y * 64;
  const int col0 = blockIdx.x * 64;
  f32x4 acc[4];
#pragma unroll
  for (int s = 0; s < 4; ++s) acc[s] = (f32x4){0.f, 0.f, 0.f, 0.f};
  const int sr = tid >> 2, sq = tid & 3;  // stage: 64 rows x 4 quads of 8 bf16

  for (int kt = 0; kt < DIMV; kt += 32) {
    *reinterpret_cast<short8v*>(&As[sr * 40 + sq * 8]) =
        *reinterpret_cast<const short8v*>(&zh[(size_t)(row0 + sr) * DIMV + kt + sq * 8]);
    *reinterpret_cast<short8v*>(&Bs[sr * 40 + sq * 8]) =
        *reinterpret_cast<const short8v*>(&ch[(size_t)(col0 + sr) * DIMV + kt + sq * 8]);
    __syncthreads();
    short8v a = *reinterpret_cast<const short8v*>(&As[(w * 16 + (l & 15)) * 40 + (l >> 4) * 8]);
#pragma unroll
    for (int s = 0; s < 4; ++s) {
      short8v b = *reinterpret_cast<const short8v*>(&Bs[(s * 16 + (l & 15)) * 40 + (l >> 4) * 8]);
      acc[s] = __builtin_amdgcn_mfma_f32_16x16x32_bf16(a, b, acc[s], 0, 0, 0);
    }
    __syncthreads();
  }
  // acc[s][j] = G(row0 + w*16 + (l>>4)*4 + j, col0 + s*16 + (l&15))
  float c2v[4];
#pragma unroll
  for (int s = 0; s < 4; ++s) c2v[s] = c2[col0 + s * 16 + (l & 15)];
  float mn[4];
#pragma unroll
  for (int j = 0; j < 4; ++j) {
    float m0 = fmaf(acc[0][j], -2.f, c2v[0]);
    float m1 = fmaf(acc[1][j], -2.f, c2v[1]);
    float m2 = fmaf(acc[2][j], -2.f, c2v[2]);
    float m3 = fmaf(acc[3][j], -2.f, c2v[3]);
    mn[j] = fminf(fminf(m0, m1), fminf(m2, m3));
  }
#pragma unroll
  for (int off = 1; off < 16; off <<= 1) {
#pragma unroll
    for (int j = 0; j < 4; ++j) mn[j] = fminf(mn[j], __shfl_xor(mn[j], off, 64));
  }
  if ((l & 15) == 0) {
    int g = l >> 4;
#pragma unroll
    for (int j = 0; j < 4; ++j)
      pv2[(size_t)(row0 + w * 16 + g * 4 + j) * 128 + blockIdx.x] = mn[j];
  }
}

// ------ per-row global min of S' + deterministic error margin -> threshold ---
// |S' - (d - z2)| <= 2*errG + fold/quant terms; errG <= 2^-8*||z||*||c||max,
// ||c||max <= sqrt(1024)/8192 = 3.906e-3 (hard bound from uniform init).
// margin = 4*errG + additive slack.
__global__ __launch_bounds__(256) void rowmin_thr(const float* __restrict__ pv2,
                                                  const float* __restrict__ z2,
                                                  float* __restrict__ thr) {
  int row = blockIdx.x * 256 + threadIdx.x;
  const float* pr = pv2 + (size_t)row * 128;
  float m = pr[0];
  for (int g = 1; g < 128; ++g) m = fminf(m, pr[g]);
  thr[row] = m + sqrtf(z2[row]) * 6.3e-5f + 8e-5f;
}

// ------ exact np-faithful rescore of flagged 64-code groups ------------------
// One wave per row. For each group with S'-min <= thr: lane t computes the
// EXACT d for code g*64+t via the proven fold chain (k ascending, folds
// {384,704,1024}, d = fl(fl(z2-2G)+c2)); lexicographic (d, idx) min = np.argmin.
__global__ __launch_bounds__(64) void rescore(const float* __restrict__ pv2,
                                              const float* __restrict__ thr,
                                              const float* __restrict__ ze,
                                              const float* __restrict__ CB,
                                              const float* __restrict__ z2,
                                              const float* __restrict__ c2,
                                              float* __restrict__ out_ids,
                                              int* __restrict__ ids,
                                              float* __restrict__ usage) {
  __shared__ float zs[1024];
  int row = blockIdx.x;
  int lane = threadIdx.x;
#pragma unroll
  for (int i = 0; i < 16; ++i) zs[lane + 64 * i] = ze[(size_t)row * DIMV + lane + 64 * i];
  __syncthreads();
  float z2v = z2[row];
  float t = thr[row];
  const float* pr = pv2 + (size_t)row * 128;
  float bestd = FLT_MAX;
  int besti = 0x7fffffff;
  for (int g = 0; g < 128; ++g) {
    if (pr[g] <= t) {  // wave-uniform branch
      int code = g * 64 + lane;
      const float* cp = CB + (size_t)code * DIMV;
      float cur = 0.f, tot = 0.f;
      for (int k = 0; k < 1024; ++k) {  // strictly ascending, np/OpenBLAS chain
        cur = fmaf(zs[k], cp[k], cur);
        if (k == 383 || k == 703 || k == 1023) { tot = __fadd_rn(tot, cur); cur = 0.f; }
      }
      float d = __fadd_rn(__fsub_rn(z2v, __fmul_rn(2.f, tot)), c2[code]);
      if (d < bestd || (d == bestd && code < besti)) { bestd = d; besti = code; }
    }
  }
#pragma unroll
  for (int off = 32; off > 0; off >>= 1) {
    float dv = __shfl_xor(bestd, off, 64);
    int iv = __shfl_xor(besti, off, 64);
    if (dv < bestd || (dv == bestd && iv < besti)) { bestd = dv; besti = iv; }
  }
  if (lane == 0) {
    ids[row] = besti;
    out_ids[row] = (float)besti;
    atomicAdd(&usage[besti], 1.0f);  // exact integer-valued floats
  }
}

// ---------------- z_q = codebook[ids] (float32 out) ----------------
__global__ __launch_bounds__(256) void gather_kernel(const int* __restrict__ ids,
                                                     const float* __restrict__ CB,
                                                     float* __restrict__ zq) {
  int row = blockIdx.x;
  int id = ids[row];
  *reinterpret_cast<float4*>(&zq[(size_t)row * DIMV + threadIdx.x * 4]) =
      *reinterpret_cast<const float4*>(&CB[(size_t)id * DIMV + threadIdx.x * 4]);
}

// -------- decoder GEMM 1: h = CB[ids] @ Wd + bd (plain fp32) ---------
__global__ __launch_bounds__(256) void gemm_dec1(const int* __restrict__ ids,
                                                 const float* __restrict__ CB,
                                                 const float* __restrict__ B,
                                                 const float* __restrict__ bias,
                                                 float* __restrict__ C) {
  __shared__ float As[32][68];
  __shared__ float Bs[32][68];
  __shared__ int sid[64];
  const int tid = threadIdx.x;
  const int tx = tid & 15, ty = tid >> 4;
  const int row0 = blockIdx.y * 64;
  const int col0 = blockIdx.x * 64;
  if (tid < 64) sid[tid] = ids[row0 + tid];
  __syncthreads();
  float acc[4][4];
#pragma unroll
  for (int i = 0; i < 4; ++i)
#pragma unroll
    for (int j = 0; j < 4; ++j) acc[i][j] = 0.f;

  for (int k0 = 0; k0 < DIMV; k0 += 32) {
#pragma unroll
    for (int l = 0; l < 2; ++l) {
      int s = tid + 256 * l;
      int r = s >> 3;
      int kq = (s & 7) << 2;
      float4 v = *reinterpret_cast<const float4*>(&CB[(size_t)sid[r] * DIMV + k0 + kq]);
      As[kq + 0][r] = v.x; As[kq + 1][r] = v.y; As[kq + 2][r] = v.z; As[kq + 3][r] = v.w;
    }
#pragma unroll
    for (int l = 0; l < 2; ++l) {
      int s = tid + 256 * l;
      int kr = s >> 4;
      int c4 = (s & 15) << 2;
      *reinterpret_cast<float4*>(&Bs[kr][c4]) =
          *reinterpret_cast<const float4*>(&B[(size_t)(k0 + kr) * DIMV + col0 + c4]);
    }
    __syncthreads();
#pragma unroll
    for (int kk = 0; kk < 32; ++kk) {
      float4 a = *reinterpret_cast<const float4*>(&As[kk][ty * 4]);
      float4 b = *reinterpret_cast<const float4*>(&Bs[kk][tx * 4]);
      float da[4] = {a.x, a.y, a.z, a.w};
      float db[4] = {b.x, b.y, b.z, b.w};
#pragma unroll
      for (int i = 0; i < 4; ++i)
#pragma unroll
        for (int j = 0; j < 4; ++j) acc[i][j] = fmaf(da[i], db[j], acc[i][j]);
    }
    __syncthreads();
  }
#pragma unroll
  for (int i = 0; i < 4; ++i) {
    int row = row0 + ty * 4 + i;
#pragma unroll
    for (int j = 0; j < 4; ++j) {
      int col = col0 + tx * 4 + j;
      C[(size_t)row * DIMV + col] = acc[i][j] + bias[col];
    }
  }
}

// -- decoder GEMM 2: recon = h @ Wo + bo (f32 out) + fused recon-loss partial --
__global__ __launch_bounds__(256) void gemm_dec2(const float* __restrict__ A,
                                                 const float* __restrict__ B,
                                                 const float* __restrict__ bias,
                                                 const float* __restrict__ roi,
                                                 float* __restrict__ Cout,
                                                 float* __restrict__ part) {
  __shared__ float As[32][68];
  __shared__ float Bs[32][68];
  __shared__ float sm[4];
  const int tid = threadIdx.x;
  const int tx = tid & 15, ty = tid >> 4;
  const int row0 = blockIdx.y * 64;
  const int col0 = blockIdx.x * 64;
  float acc[4][4];
#pragma unroll
  for (int i = 0; i < 4; ++i)
#pragma unroll
    for (int j = 0; j < 4; ++j) acc[i][j] = 0.f;

  for (int k0 = 0; k0 < DIMV; k0 += 32) {
#pragma unroll
    for (int l = 0; l < 2; ++l) {
      int s = tid + 256 * l;
      int r = s >> 3;
      int kq = (s & 7) << 2;
      float4 v = *reinterpret_cast<const float4*>(&A[(size_t)(row0 + r) * DIMV + k0 + kq]);
      As[kq + 0][r] = v.x; As[kq + 1][r] = v.y; As[kq + 2][r] = v.z; As[kq + 3][r] = v.w;
    }
#pragma unroll
    for (int l = 0; l < 2; ++l) {
      int s = tid + 256 * l;
      int kr = s >> 4;
      int c4 = (s & 15) << 2;
      *reinterpret_cast<float4*>(&Bs[kr][c4]) =
          *reinterpret_cast<const float4*>(&B[(size_t)(k0 + kr) * INDIM + col0 + c4]);
    }
    __syncthreads();
#pragma unroll
    for (int kk = 0; kk < 32; ++kk) {
      float4 a = *reinterpret_cast<const float4*>(&As[kk][ty * 4]);
      float4 b = *reinterpret_cast<const float4*>(&Bs[kk][tx * 4]);
      float da[4] = {a.x, a.y, a.z, a.w};
      float db[4] = {b.x, b.y, b.z, b.w};
#pragma unroll
      for (int i = 0; i < 4; ++i)
#pragma unroll
        for (int j = 0; j < 4; ++j) acc[i][j] = fmaf(da[i], db[j], acc[i][j]);
    }
    __syncthreads();
  }

  float s = 0.f;
#pragma unroll
  for (int i = 0; i < 4; ++i) {
    int row = row0 + ty * 4 + i;
    int col = col0 + tx * 4;
    float4 x = *reinterpret_cast<const float4*>(&roi[(size_t)row * INDIM + col]);
    float xs[4] = {x.x, x.y, x.z, x.w};
    float vals[4];
#pragma unroll
    for (int j = 0; j < 4; ++j) {
      float val = acc[i][j] + bias[col + j];
      float d = val - clip10(xs[j]);
      s += d * d;
      vals[j] = val;
    }
    *reinterpret_cast<float4*>(&Cout[(size_t)row * INDIM + col]) =
        make_float4(vals[0], vals[1], vals[2], vals[3]);
  }
  float t = block_sum256(s, sm);
  if (tid == 0) part[blockIdx.y * gridDim.x + blockIdx.x] = t;
}

// ---------------- embedding loss partial: sum((CB[id]-ze)^2) per row ---------
__global__ __launch_bounds__(256) void emb_partial(const int* __restrict__ ids,
                                                   const float* __restrict__ CB,
                                                   const float* __restrict__ ze,
                                                   float* __restrict__ part) {
  __shared__ float sm[4];
  int row = blockIdx.x;
  int id = ids[row];
  float4 q = *reinterpret_cast<const float4*>(&CB[(size_t)id * DIMV + threadIdx.x * 4]);
  float4 z = *reinterpret_cast<const float4*>(&ze[(size_t)row * DIMV + threadIdx.x * 4]);
  float dx = q.x - z.x, dy = q.y - z.y, dz = q.z - z.z, dw = q.w - z.w;
  float t = block_sum256(dx * dx + dy * dy + dz * dz + dw * dw, sm);
  if (threadIdx.x == 0) part[row] = t;
}

// ---------------- final reduce: 4 scalar losses ------------------------------
__global__ __launch_bounds__(256) void loss_final(const float* __restrict__ part1,
                                                  const float* __restrict__ part2,
                                                  float* __restrict__ scal) {
  __shared__ float sm[4];
  float s1 = 0.f;
  for (int i = threadIdx.x; i < 8192; i += 256) s1 += part1[i];
  float s2 = 0.f;
  for (int i = threadIdx.x; i < NROWS; i += 256) s2 += part2[i];
  float t1 = block_sum256(s1, sm);
  __syncthreads();
  float t2 = block_sum256(s2, sm);
  if (threadIdx.x == 0) {
    float recon_loss = t1 / 33554432.f;  // N * INDIM
    float emb = t2 / 16777216.f;         // N * DIM
    scal[0] = recon_loss + emb + 0.25f * emb;  // vq = recon + embed + 0.25*commit
    scal[1] = recon_loss;
    scal[2] = emb;
    scal[3] = emb;  // commitment forward value == embedding
  }
}

extern "C" void kernel_launch(void* const* d_in, const int* in_sizes, int n_in,
                              void* d_out, int out_size, void* d_ws, size_t ws_size,
                              hipStream_t stream) {
  const float* roi = (const float*)d_in[0];
  const float* Wp = (const float*)d_in[1];
  const float* bp = (const float*)d_in[2];
  const float* We = (const float*)d_in[3];
  const float* be = (const float*)d_in[4];
  const float* CB = (const float*)d_in[5];
  const float* Wd = (const float*)d_in[6];
  const float* bd = (const float*)d_in[7];
  const float* Wo = (const float*)d_in[8];
  const float* bo = (const float*)d_in[9];

  // float32 output layout: ids[N], z_q[N*DIM], recon[N*INDIM], 4 scalars, usage
  float* out = (float*)d_out;
  float* out_ids = out;
  float* out_zq = out + NROWS;
  float* out_recon = out_zq + (size_t)NROWS * DIMV;
  float* out_scal = out_recon + (size_t)NROWS * INDIM;
  float* out_usage = out_scal + 4;

  // workspace (~137 MB) — zh/ch/pv2/thr alias z1 (dead between ze and dec1)
  float* ws = (float*)d_ws;
  float* z1 = ws;                                   // N*DIM (reused as h)
  float* ze = z1 + (size_t)NROWS * DIMV;            // N*DIM
  float* z2 = ze + (size_t)NROWS * DIMV;            // N
  float* c2 = z2 + NROWS;                           // NCODE
  int* ids = (int*)(c2 + NCODE);                    // N
  float* part1 = (float*)(ids + NROWS);             // 8192 (recon partials)
  float* part2 = part1 + 8192;                      // N (emb partials)
  unsigned short* zh = (unsigned short*)z1;                                   // N*DIM bf16
  unsigned short* ch = ((unsigned short*)z1) + (size_t)NROWS * DIMV;          // NCODE*DIM bf16
  float* pv2 = z1 + (size_t)NROWS * DIMV / 2 + (size_t)NCODE * DIMV / 2;      // N*128
  float* thr = pv2 + (size_t)NROWS * 128;                                     // N

  zero_kernel<<<32, 256, 0, stream>>>(out_usage, NCODE);  // idempotent per call

  // z1 = clip(roi) @ Wp + bp ; z_e = z1 @ We + be  (np/OpenBLAS-faithful fp32)
  gemm_np<0, true><<<dim3(DIMV / 64, NROWS / 64), 256, 0, stream>>>(roi, Wp, bp, z1, NROWS,
                                                                    DIMV, INDIM);
  gemm_np<1, false><<<dim3(DIMV / 64, NROWS / 64), 256, 0, stream>>>(z1, We, be, ze, NROWS,
                                                                     DIMV, DIMV);
  // z2 = np.sum(z_e*z_e,1), c2 = np.sum(CB*CB,1)  (numpy pairwise emulation)
  rowsq_np<<<NROWS / 256, 256, 0, stream>>>(ze, NROWS, z2);
  rowsq_np<<<NCODE / 256, 256, 0, stream>>>(CB, NCODE, c2);

  // bf16 MFMA filter: group minima of S' -> threshold -> exact np rescore
  tobf16_kernel<<<NROWS * DIMV / 4 / 256, 256, 0, stream>>>(ze, zh, NROWS * DIMV / 4);
  tobf16_kernel<<<NCODE * DIMV / 4 / 256, 256, 0, stream>>>(CB, ch, NCODE * DIMV / 4);
  mfma_filter<<<dim3(NCODE / 64, NROWS / 64), 256, 0, stream>>>(zh, ch, c2, pv2);
  rowmin_thr<<<NROWS / 256, 256, 0, stream>>>(pv2, z2, thr);
  rescore<<<NROWS, 64, 0, stream>>>(pv2, thr, ze, CB, z2, c2, out_ids, ids, out_usage);

  gather_kernel<<<NROWS, 256, 0, stream>>>(ids, CB, out_zq);

  // decoder: h = CB[ids] @ Wd + bd ; recon = h @ Wo + bo (+ fused recon-loss)
  gemm_dec1<<<dim3(DIMV / 64, NROWS / 64), 256, 0, stream>>>(ids, CB, Wd, bd, z1);
  gemm_dec2<<<dim3(INDIM / 64, NROWS / 64), 256, 0, stream>>>(z1, Wo, bo, roi, out_recon,
                                                              part1);
  // embedding loss partials + final scalars
  emb_partial<<<NROWS, 256, 0, stream>>>(ids, CB, ze, part2);
  loss_final<<<1, 256, 0, stream>>>(part1, part2, out_scal);
}

// Round 13
// 4876.476 us; speedup vs baseline: 4.0477x; 4.0477x over previous
//
#include <hip/hip_runtime.h>
#include <hip/hip_bf16.h>
#include <cfloat>

// Problem constants
#define NROWS 16384
#define INDIM 2048
#define DIMV  1024
#define NCODE 8192

typedef __attribute__((ext_vector_type(8))) _Float16 half8v;
typedef __attribute__((ext_vector_type(4))) _Float16 half4v;
typedef __attribute__((ext_vector_type(4))) float f32x4;

__device__ inline float clip10(float x) { return fminf(fmaxf(x, -10.f), 10.f); }

__device__ inline float block_sum256(float v, float* sm) {
#pragma unroll
  for (int off = 32; off > 0; off >>= 1) v += __shfl_down(v, off, 64);
  int lane = threadIdx.x & 63, w = threadIdx.x >> 6;
  if (lane == 0) sm[w] = v;
  __syncthreads();
  float r = 0.f;
  if (threadIdx.x == 0) r = sm[0] + sm[1] + sm[2] + sm[3];
  return r;  // valid on thread 0 only
}

__global__ void zero_kernel(float* __restrict__ p, int n) {
  int i = blockIdx.x * 256 + threadIdx.x;
  if (i < n) p[i] = 0.f;
}

// OpenBLAS level3 K-panel boundaries (GEMM_Q=384, halving rule):
//   K=2048 -> 384,384,384,384,256,256 ; K=1024 -> 384,320,320
template <int KSEL>
__device__ inline bool kfold(int kend) {
  if (KSEL == 0)
    return kend == 384 || kend == 768 || kend == 1152 || kend == 1536 || kend == 1792 ||
           kend == 2048;
  return kend == 384 || kend == 704 || kend == 1024;
}

// ============== np-faithful fp32 GEMM: C = op(A)@B + bias ==================
template <int KSEL, bool CLIP>
__global__ __launch_bounds__(256) void gemm_np(const float* __restrict__ A,
                                               const float* __restrict__ B,
                                               const float* __restrict__ bias,
                                               float* __restrict__ C, int M, int N, int K) {
  __shared__ float As[32][68];  // [k][m]
  __shared__ float Bs[32][68];  // [k][n]
  const int tid = threadIdx.x;
  const int tx = tid & 15, ty = tid >> 4;
  const int row0 = blockIdx.y * 64;
  const int col0 = blockIdx.x * 64;
  float cur[4][4], tot[4][4];
#pragma unroll
  for (int i = 0; i < 4; ++i)
#pragma unroll
    for (int j = 0; j < 4; ++j) { cur[i][j] = 0.f; tot[i][j] = 0.f; }

  for (int k0 = 0; k0 < K; k0 += 32) {
#pragma unroll
    for (int l = 0; l < 2; ++l) {
      int s = tid + 256 * l;
      int r = s >> 3;
      int kq = (s & 7) << 2;
      float4 v = *reinterpret_cast<const float4*>(&A[(size_t)(row0 + r) * K + k0 + kq]);
      if (CLIP) { v.x = clip10(v.x); v.y = clip10(v.y); v.z = clip10(v.z); v.w = clip10(v.w); }
      As[kq + 0][r] = v.x; As[kq + 1][r] = v.y; As[kq + 2][r] = v.z; As[kq + 3][r] = v.w;
    }
#pragma unroll
    for (int l = 0; l < 2; ++l) {
      int s = tid + 256 * l;
      int kr = s >> 4;
      int c4 = (s & 15) << 2;
      *reinterpret_cast<float4*>(&Bs[kr][c4]) =
          *reinterpret_cast<const float4*>(&B[(size_t)(k0 + kr) * N + col0 + c4]);
    }
    __syncthreads();
#pragma unroll
    for (int kk = 0; kk < 32; ++kk) {  // k strictly ascending
      float4 a = *reinterpret_cast<const float4*>(&As[kk][ty * 4]);
      float4 b = *reinterpret_cast<const float4*>(&Bs[kk][tx * 4]);
      float da[4] = {a.x, a.y, a.z, a.w};
      float db[4] = {b.x, b.y, b.z, b.w};
#pragma unroll
      for (int i = 0; i < 4; ++i)
#pragma unroll
        for (int j = 0; j < 4; ++j) cur[i][j] = fmaf(da[i], db[j], cur[i][j]);
    }
    __syncthreads();
    if (kfold<KSEL>(k0 + 32)) {
#pragma unroll
      for (int i = 0; i < 4; ++i)
#pragma unroll
        for (int j = 0; j < 4; ++j) { tot[i][j] = __fadd_rn(tot[i][j], cur[i][j]); cur[i][j] = 0.f; }
    }
  }
#pragma unroll
  for (int i = 0; i < 4; ++i) {
    int row = row0 + ty * 4 + i;
#pragma unroll
    for (int j = 0; j < 4; ++j) {
      int col = col0 + tx * 4 + j;
      C[(size_t)row * N + col] = __fadd_rn(tot[i][j], bias[col]);
    }
  }
}

// ===== numpy pairwise row-sum of squares (AVX-512 base-case emulation) ======
__global__ __launch_bounds__(256) void rowsq_np(const float* __restrict__ X, int nrows,
                                                float* __restrict__ out) {
  int row = blockIdx.x * 256 + threadIdx.x;
  if (row >= nrows) return;
  const float* rp = X + (size_t)row * 1024;
  float Bres[8];
#pragma unroll
  for (int blk = 0; blk < 8; ++blk) {
    const float* p = rp + blk * 128;
    float x[16];
#pragma unroll
    for (int L = 0; L < 16; ++L) {
      float m0 = __fmul_rn(p[L], p[L]);
      float m1 = __fmul_rn(p[64 + L], p[64 + L]);
      float r0 = __fadd_rn(m0, m1);
      float m2 = __fmul_rn(p[16 + L], p[16 + L]);
      float m3 = __fmul_rn(p[80 + L], p[80 + L]);
      float r1 = __fadd_rn(m2, m3);
      float m4 = __fmul_rn(p[32 + L], p[32 + L]);
      float m5 = __fmul_rn(p[96 + L], p[96 + L]);
      float r2 = __fadd_rn(m4, m5);
      float m6 = __fmul_rn(p[48 + L], p[48 + L]);
      float m7 = __fmul_rn(p[112 + L], p[112 + L]);
      float r3 = __fadd_rn(m6, m7);
      x[L] = __fadd_rn(__fadd_rn(r0, r1), __fadd_rn(r2, r3));
    }
    float z[4];
#pragma unroll
    for (int i = 0; i < 4; ++i)
      z[i] = __fadd_rn(__fadd_rn(x[i], x[i + 8]), __fadd_rn(x[i + 4], x[i + 12]));
    Bres[blk] = __fadd_rn(__fadd_rn(z[0], z[2]), __fadd_rn(z[1], z[3]));
  }
  float s01 = __fadd_rn(Bres[0], Bres[1]);
  float s23 = __fadd_rn(Bres[2], Bres[3]);
  float s45 = __fadd_rn(Bres[4], Bres[5]);
  float s67 = __fadd_rn(Bres[6], Bres[7]);
  out[row] = __fadd_rn(__fadd_rn(s01, s23), __fadd_rn(s45, s67));
}

// ---------------- fp32 -> fp16 (RNE) with compile-time power-of-2 scale -----
template <int SCALE>
__global__ __launch_bounds__(256) void tofp16_kernel(const float* __restrict__ x,
                                                     _Float16* __restrict__ y, int n4) {
  int i = blockIdx.x * 256 + threadIdx.x;
  if (i >= n4) return;
  float4 v = *reinterpret_cast<const float4*>(x + (size_t)i * 4);
  half4v o;
  o.x = (_Float16)(v.x * (float)SCALE);
  o.y = (_Float16)(v.y * (float)SCALE);
  o.z = (_Float16)(v.z * (float)SCALE);
  o.w = (_Float16)(v.w * (float)SCALE);
  *reinterpret_cast<half4v*>(y + (size_t)i * 4) = o;
}

// ====== fp16 MFMA filter: per-(row, 32-code-group) min of scaled score ======
// S'_scaled = -2*(zh . ch) + c2*8192, where ch = fp16(c*8192) (exact scale).
// Tile 64 rows x 64 codes (=2 groups), 4 waves x (16 rows x 64 codes).
// Fragment layouts (m89/m91 HW-verified, dtype-independent): A row = lane&15,
// k-slice = (lane>>4)*8; B col = lane&15; C/D col = lane&15, row = (l>>4)*4+reg.
__global__ __launch_bounds__(256) void mfma_filter(const _Float16* __restrict__ zh,
                                                   const _Float16* __restrict__ ch,
                                                   const float* __restrict__ c2,
                                                   _Float16* __restrict__ pv2) {
  __shared__ _Float16 As[64 * 40];
  __shared__ _Float16 Bs[64 * 40];
  const int tid = threadIdx.x;
  const int w = tid >> 6, l = tid & 63;
  const int row0 = blockIdx.y * 64;
  const int col0 = blockIdx.x * 64;
  f32x4 acc[4];
#pragma unroll
  for (int s = 0; s < 4; ++s) acc[s] = (f32x4){0.f, 0.f, 0.f, 0.f};
  const int sr = tid >> 2, sq = tid & 3;  // stage: 64 rows x 4 quads of 8 fp16

  for (int kt = 0; kt < DIMV; kt += 32) {
    *reinterpret_cast<half8v*>(&As[sr * 40 + sq * 8]) =
        *reinterpret_cast<const half8v*>(&zh[(size_t)(row0 + sr) * DIMV + kt + sq * 8]);
    *reinterpret_cast<half8v*>(&Bs[sr * 40 + sq * 8]) =
        *reinterpret_cast<const half8v*>(&ch[(size_t)(col0 + sr) * DIMV + kt + sq * 8]);
    __syncthreads();
    half8v a = *reinterpret_cast<const half8v*>(&As[(w * 16 + (l & 15)) * 40 + (l >> 4) * 8]);
#pragma unroll
    for (int s = 0; s < 4; ++s) {
      half8v b = *reinterpret_cast<const half8v*>(&Bs[(s * 16 + (l & 15)) * 40 + (l >> 4) * 8]);
      acc[s] = __builtin_amdgcn_mfma_f32_16x16x32_f16(a, b, acc[s], 0, 0, 0);
    }
    __syncthreads();
  }
  // acc[s][j] = 8192*G(row0 + w*16 + (l>>4)*4 + j, col0 + s*16 + (l&15))
  float c2s[4];
#pragma unroll
  for (int s = 0; s < 4; ++s) c2s[s] = c2[col0 + s * 16 + (l & 15)] * 8192.f;
  float mnp[2][4];
#pragma unroll
  for (int j = 0; j < 4; ++j) {
    mnp[0][j] = fminf(fmaf(acc[0][j], -2.f, c2s[0]), fmaf(acc[1][j], -2.f, c2s[1]));
    mnp[1][j] = fminf(fmaf(acc[2][j], -2.f, c2s[2]), fmaf(acc[3][j], -2.f, c2s[3]));
  }
#pragma unroll
  for (int off = 1; off < 16; off <<= 1) {
#pragma unroll
    for (int p = 0; p < 2; ++p)
#pragma unroll
      for (int j = 0; j < 4; ++j) mnp[p][j] = fminf(mnp[p][j], __shfl_xor(mnp[p][j], off, 64));
  }
  if ((l & 15) == 0) {
    int q = l >> 4;
#pragma unroll
    for (int p = 0; p < 2; ++p)
#pragma unroll
      for (int j = 0; j < 4; ++j)
        pv2[(size_t)(row0 + w * 16 + q * 4 + j) * 256 + blockIdx.x * 2 + p] =
            (_Float16)mnp[p][j];
  }
}

// ------ per-row global min of S'_scaled + rigorous error margin -> thr -------
// E <= 2*2^-10*||z||*||c||max + delta_np + slack; ||c||max <= 32/8192 (hard).
// thr_scaled = m + 1.5*(2E)*8192 = m + (sqrt(z2)*2.3e-5 + 4e-5)*8192.
__global__ __launch_bounds__(256) void rowmin_thr(const _Float16* __restrict__ pv2,
                                                  const float* __restrict__ z2,
                                                  float* __restrict__ thr) {
  int row = blockIdx.x * 256 + threadIdx.x;
  const _Float16* pr = pv2 + (size_t)row * 256;
  float m = (float)pr[0];
  for (int g = 1; g < 256; ++g) m = fminf(m, (float)pr[g]);
  thr[row] = m + (sqrtf(z2[row]) * 2.3e-5f + 4.0e-5f) * 8192.f;
}

// ------ exact np-faithful rescore of flagged 32-code groups ------------------
// One wave per row: ballot over 256 group-minima, iterate flagged groups
// ascending; lane&31 = code in group; exact fold chain (k ascending, folds
// {384,704,1024}, d = fl(fl(z2-2G)+c2)); lexicographic (d, idx) = np.argmin.
__global__ __launch_bounds__(64) void rescore(const _Float16* __restrict__ pv2,
                                              const float* __restrict__ thr,
                                              const float* __restrict__ ze,
                                              const float* __restrict__ CB,
                                              const float* __restrict__ z2,
                                              const float* __restrict__ c2,
                                              float* __restrict__ out_ids,
                                              int* __restrict__ ids,
                                              float* __restrict__ usage) {
  __shared__ float zs[1024];
  int row = blockIdx.x;
  int lane = threadIdx.x;
#pragma unroll
  for (int i = 0; i < 16; ++i) zs[lane + 64 * i] = ze[(size_t)row * DIMV + lane + 64 * i];
  __syncthreads();
  float z2v = z2[row];
  float t = thr[row];
  const _Float16* pr = pv2 + (size_t)row * 256;
  float bestd = FLT_MAX;
  int besti = 0x7fffffff;
  for (int base = 0; base < 256; base += 64) {
    unsigned long long mask = __ballot((float)pr[base + lane] <= t);
    while (mask) {
      int g = __builtin_ctzll(mask);
      mask &= mask - 1;
      int code = (base + g) * 32 + (lane & 31);  // lanes 32-63 duplicate (harmless)
      const float* cp = CB + (size_t)code * DIMV;
      float cur = 0.f, tot = 0.f;
      for (int k = 0; k < 384; ++k) cur = fmaf(zs[k], cp[k], cur);
      tot = __fadd_rn(tot, cur); cur = 0.f;
      for (int k = 384; k < 704; ++k) cur = fmaf(zs[k], cp[k], cur);
      tot = __fadd_rn(tot, cur); cur = 0.f;
      for (int k = 704; k < 1024; ++k) cur = fmaf(zs[k], cp[k], cur);
      tot = __fadd_rn(tot, cur);
      float d = __fadd_rn(__fsub_rn(z2v, __fmul_rn(2.f, tot)), c2[code]);
      if (d < bestd || (d == bestd && code < besti)) { bestd = d; besti = code; }
    }
  }
#pragma unroll
  for (int off = 32; off > 0; off >>= 1) {
    float dv = __shfl_xor(bestd, off, 64);
    int iv = __shfl_xor(besti, off, 64);
    if (dv < bestd || (dv == bestd && iv < besti)) { bestd = dv; besti = iv; }
  }
  if (lane == 0) {
    ids[row] = besti;
    out_ids[row] = (float)besti;
    atomicAdd(&usage[besti], 1.0f);  // exact integer-valued floats
  }
}

// ---------------- z_q = codebook[ids] (float32 out) ----------------
__global__ __launch_bounds__(256) void gather_kernel(const int* __restrict__ ids,
                                                     const float* __restrict__ CB,
                                                     float* __restrict__ zq) {
  int row = blockIdx.x;
  int id = ids[row];
  *reinterpret_cast<float4*>(&zq[(size_t)row * DIMV + threadIdx.x * 4]) =
      *reinterpret_cast<const float4*>(&CB[(size_t)id * DIMV + threadIdx.x * 4]);
}

// -------- decoder GEMM 1: h = CB[ids] @ Wd + bd (plain fp32) ---------
__global__ __launch_bounds__(256) void gemm_dec1(const int* __restrict__ ids,
                                                 const float* __restrict__ CB,
                                                 const float* __restrict__ B,
                                                 const float* __restrict__ bias,
                                                 float* __restrict__ C) {
  __shared__ float As[32][68];
  __shared__ float Bs[32][68];
  __shared__ int sid[64];
  const int tid = threadIdx.x;
  const int tx = tid & 15, ty = tid >> 4;
  const int row0 = blockIdx.y * 64;
  const int col0 = blockIdx.x * 64;
  if (tid < 64) sid[tid] = ids[row0 + tid];
  __syncthreads();
  float acc[4][4];
#pragma unroll
  for (int i = 0; i < 4; ++i)
#pragma unroll
    for (int j = 0; j < 4; ++j) acc[i][j] = 0.f;

  for (int k0 = 0; k0 < DIMV; k0 += 32) {
#pragma unroll
    for (int l = 0; l < 2; ++l) {
      int s = tid + 256 * l;
      int r = s >> 3;
      int kq = (s & 7) << 2;
      float4 v = *reinterpret_cast<const float4*>(&CB[(size_t)sid[r] * DIMV + k0 + kq]);
      As[kq + 0][r] = v.x; As[kq + 1][r] = v.y; As[kq + 2][r] = v.z; As[kq + 3][r] = v.w;
    }
#pragma unroll
    for (int l = 0; l < 2; ++l) {
      int s = tid + 256 * l;
      int kr = s >> 4;
      int c4 = (s & 15) << 2;
      *reinterpret_cast<float4*>(&Bs[kr][c4]) =
          *reinterpret_cast<const float4*>(&B[(size_t)(k0 + kr) * DIMV + col0 + c4]);
    }
    __syncthreads();
#pragma unroll
    for (int kk = 0; kk < 32; ++kk) {
      float4 a = *reinterpret_cast<const float4*>(&As[kk][ty * 4]);
      float4 b = *reinterpret_cast<const float4*>(&Bs[kk][tx * 4]);
      float da[4] = {a.x, a.y, a.z, a.w};
      float db[4] = {b.x, b.y, b.z, b.w};
#pragma unroll
      for (int i = 0; i < 4; ++i)
#pragma unroll
        for (int j = 0; j < 4; ++j) acc[i][j] = fmaf(da[i], db[j], acc[i][j]);
    }
    __syncthreads();
  }
#pragma unroll
  for (int i = 0; i < 4; ++i) {
    int row = row0 + ty * 4 + i;
#pragma unroll
    for (int j = 0; j < 4; ++j) {
      int col = col0 + tx * 4 + j;
      C[(size_t)row * DIMV + col] = acc[i][j] + bias[col];
    }
  }
}

// -- decoder GEMM 2: recon = h @ Wo + bo (f32 out) + fused recon-loss partial --
__global__ __launch_bounds__(256) void gemm_dec2(const float* __restrict__ A,
                                                 const float* __restrict__ B,
                                                 const float* __restrict__ bias,
                                                 const float* __restrict__ roi,
                                                 float* __restrict__ Cout,
                                                 float* __restrict__ part) {
  __shared__ float As[32][68];
  __shared__ float Bs[32][68];
  __shared__ float sm[4];
  const int tid = threadIdx.x;
  const int tx = tid & 15, ty = tid >> 4;
  const int row0 = blockIdx.y * 64;
  const int col0 = blockIdx.x * 64;
  float acc[4][4];
#pragma unroll
  for (int i = 0; i < 4; ++i)
#pragma unroll
    for (int j = 0; j < 4; ++j) acc[i][j] = 0.f;

  for (int k0 = 0; k0 < DIMV; k0 += 32) {
#pragma unroll
    for (int l = 0; l < 2; ++l) {
      int s = tid + 256 * l;
      int r = s >> 3;
      int kq = (s & 7) << 2;
      float4 v = *reinterpret_cast<const float4*>(&A[(size_t)(row0 + r) * DIMV + k0 + kq]);
      As[kq + 0][r] = v.x; As[kq + 1][r] = v.y; As[kq + 2][r] = v.z; As[kq + 3][r] = v.w;
    }
#pragma unroll
    for (int l = 0; l < 2; ++l) {
      int s = tid + 256 * l;
      int kr = s >> 4;
      int c4 = (s & 15) << 2;
      *reinterpret_cast<float4*>(&Bs[kr][c4]) =
          *reinterpret_cast<const float4*>(&B[(size_t)(k0 + kr) * INDIM + col0 + c4]);
    }
    __syncthreads();
#pragma unroll
    for (int kk = 0; kk < 32; ++kk) {
      float4 a = *reinterpret_cast<const float4*>(&As[kk][ty * 4]);
      float4 b = *reinterpret_cast<const float4*>(&Bs[kk][tx * 4]);
      float da[4] = {a.x, a.y, a.z, a.w};
      float db[4] = {b.x, b.y, b.z, b.w};
#pragma unroll
      for (int i = 0; i < 4; ++i)
#pragma unroll
        for (int j = 0; j < 4; ++j) acc[i][j] = fmaf(da[i], db[j], acc[i][j]);
    }
    __syncthreads();
  }

  float s = 0.f;
#pragma unroll
  for (int i = 0; i < 4; ++i) {
    int row = row0 + ty * 4 + i;
    int col = col0 + tx * 4;
    float4 x = *reinterpret_cast<const float4*>(&roi[(size_t)row * INDIM + col]);
    float xs[4] = {x.x, x.y, x.z, x.w};
    float vals[4];
#pragma unroll
    for (int j = 0; j < 4; ++j) {
      float val = acc[i][j] + bias[col + j];
      float d = val - clip10(xs[j]);
      s += d * d;
      vals[j] = val;
    }
    *reinterpret_cast<float4*>(&Cout[(size_t)row * INDIM + col]) =
        make_float4(vals[0], vals[1], vals[2], vals[3]);
  }
  float t = block_sum256(s, sm);
  if (tid == 0) part[blockIdx.y * gridDim.x + blockIdx.x] = t;
}

// ---------------- embedding loss partial: sum((CB[id]-ze)^2) per row ---------
__global__ __launch_bounds__(256) void emb_partial(const int* __restrict__ ids,
                                                   const float* __restrict__ CB,
                                                   const float* __restrict__ ze,
                                                   float* __restrict__ part) {
  __shared__ float sm[4];
  int row = blockIdx.x;
  int id = ids[row];
  float4 q = *reinterpret_cast<const float4*>(&CB[(size_t)id * DIMV + threadIdx.x * 4]);
  float4 z = *reinterpret_cast<const float4*>(&ze[(size_t)row * DIMV + threadIdx.x * 4]);
  float dx = q.x - z.x, dy = q.y - z.y, dz = q.z - z.z, dw = q.w - z.w;
  float t = block_sum256(dx * dx + dy * dy + dz * dz + dw * dw, sm);
  if (threadIdx.x == 0) part[row] = t;
}

// ---------------- final reduce: 4 scalar losses ------------------------------
__global__ __launch_bounds__(256) void loss_final(const float* __restrict__ part1,
                                                  const float* __restrict__ part2,
                                                  float* __restrict__ scal) {
  __shared__ float sm[4];
  float s1 = 0.f;
  for (int i = threadIdx.x; i < 8192; i += 256) s1 += part1[i];
  float s2 = 0.f;
  for (int i = threadIdx.x; i < NROWS; i += 256) s2 += part2[i];
  float t1 = block_sum256(s1, sm);
  __syncthreads();
  float t2 = block_sum256(s2, sm);
  if (threadIdx.x == 0) {
    float recon_loss = t1 / 33554432.f;  // N * INDIM
    float emb = t2 / 16777216.f;         // N * DIM
    scal[0] = recon_loss + emb + 0.25f * emb;  // vq = recon + embed + 0.25*commit
    scal[1] = recon_loss;
    scal[2] = emb;
    scal[3] = emb;  // commitment forward value == embedding
  }
}

extern "C" void kernel_launch(void* const* d_in, const int* in_sizes, int n_in,
                              void* d_out, int out_size, void* d_ws, size_t ws_size,
                              hipStream_t stream) {
  const float* roi = (const float*)d_in[0];
  const float* Wp = (const float*)d_in[1];
  const float* bp = (const float*)d_in[2];
  const float* We = (const float*)d_in[3];
  const float* be = (const float*)d_in[4];
  const float* CB = (const float*)d_in[5];
  const float* Wd = (const float*)d_in[6];
  const float* bd = (const float*)d_in[7];
  const float* Wo = (const float*)d_in[8];
  const float* bo = (const float*)d_in[9];

  // float32 output layout: ids[N], z_q[N*DIM], recon[N*INDIM], 4 scalars, usage
  float* out = (float*)d_out;
  float* out_ids = out;
  float* out_zq = out + NROWS;
  float* out_recon = out_zq + (size_t)NROWS * DIMV;
  float* out_scal = out_recon + (size_t)NROWS * INDIM;
  float* out_usage = out_scal + 4;

  // workspace (~137 MB); zh/ch alias z1 (dead between ze and dec1)
  float* ws = (float*)d_ws;
  float* z1 = ws;                                   // N*DIM (reused as h)
  float* ze = z1 + (size_t)NROWS * DIMV;            // N*DIM
  float* z2 = ze + (size_t)NROWS * DIMV;            // N
  float* c2 = z2 + NROWS;                           // NCODE
  int* ids = (int*)(c2 + NCODE);                    // N
  float* part1 = (float*)(ids + NROWS);             // 8192 (recon partials)
  float* part2 = part1 + 8192;                      // N (emb partials)
  _Float16* pv2 = (_Float16*)(part2 + NROWS);       // N*256 fp16 (8.4 MB)
  float* thr = (float*)(pv2 + (size_t)NROWS * 256); // N
  _Float16* zh = (_Float16*)z1;                     // N*DIM fp16 (32 MB, alias)
  _Float16* ch = zh + (size_t)NROWS * DIMV;         // NCODE*DIM fp16 (16 MB, alias)

  zero_kernel<<<32, 256, 0, stream>>>(out_usage, NCODE);  // idempotent per call

  // z1 = clip(roi) @ Wp + bp ; z_e = z1 @ We + be  (np/OpenBLAS-faithful fp32)
  gemm_np<0, true><<<dim3(DIMV / 64, NROWS / 64), 256, 0, stream>>>(roi, Wp, bp, z1, NROWS,
                                                                    DIMV, INDIM);
  gemm_np<1, false><<<dim3(DIMV / 64, NROWS / 64), 256, 0, stream>>>(z1, We, be, ze, NROWS,
                                                                     DIMV, DIMV);
  // z2 = np.sum(z_e*z_e,1), c2 = np.sum(CB*CB,1)  (numpy pairwise emulation)
  rowsq_np<<<NROWS / 256, 256, 0, stream>>>(ze, NROWS, z2);
  rowsq_np<<<NCODE / 256, 256, 0, stream>>>(CB, NCODE, c2);

  // fp16 MFMA filter (c scaled x8192) -> 32-code-group minima -> thr -> rescore
  tofp16_kernel<1><<<NROWS * DIMV / 4 / 256, 256, 0, stream>>>(ze, zh, NROWS * DIMV / 4);
  tofp16_kernel<8192><<<NCODE * DIMV / 4 / 256, 256, 0, stream>>>(CB, ch, NCODE * DIMV / 4);
  mfma_filter<<<dim3(NCODE / 64, NROWS / 64), 256, 0, stream>>>(zh, ch, c2, pv2);
  rowmin_thr<<<NROWS / 256, 256, 0, stream>>>(pv2, z2, thr);
  rescore<<<NROWS, 64, 0, stream>>>(pv2, thr, ze, CB, z2, c2, out_ids, ids, out_usage);

  gather_kernel<<<NROWS, 256, 0, stream>>>(ids, CB, out_zq);

  // decoder: h = CB[ids] @ Wd + bd ; recon = h @ Wo + bo (+ fused recon-loss)
  gemm_dec1<<<dim3(DIMV / 64, NROWS / 64), 256, 0, stream>>>(ids, CB, Wd, bd, z1);
  gemm_dec2<<<dim3(INDIM / 64, NROWS / 64), 256, 0, stream>>>(z1, Wo, bo, roi, out_recon,
                                                              part1);
  // embedding loss partials + final scalars
  emb_partial<<<NROWS, 256, 0, stream>>>(ids, CB, ze, part2);
  loss_final<<<1, 256, 0, stream>>>(part1, part2, out_scal);
}

// Round 14
// 4641.537 us; speedup vs baseline: 4.2526x; 1.0506x over previous
//
#include <hip/hip_runtime.h>
#include <hip/hip_bf16.h>
#include <cfloat>

// Problem constants
#define NROWS 16384
#define INDIM 2048
#define DIMV  1024
#define NCODE 8192

typedef __attribute__((ext_vector_type(8))) _Float16 half8v;
typedef __attribute__((ext_vector_type(4))) _Float16 half4v;
typedef __attribute__((ext_vector_type(4))) float f32x4;

__device__ inline float clip10(float x) { return fminf(fmaxf(x, -10.f), 10.f); }

__device__ inline float block_sum256(float v, float* sm) {
#pragma unroll
  for (int off = 32; off > 0; off >>= 1) v += __shfl_down(v, off, 64);
  int lane = threadIdx.x & 63, w = threadIdx.x >> 6;
  if (lane == 0) sm[w] = v;
  __syncthreads();
  float r = 0.f;
  if (threadIdx.x == 0) r = sm[0] + sm[1] + sm[2] + sm[3];
  return r;  // valid on thread 0 only
}

__global__ void zero_kernel(float* __restrict__ p, int n) {
  int i = blockIdx.x * 256 + threadIdx.x;
  if (i < n) p[i] = 0.f;
}

// OpenBLAS level3 K-panel boundaries (GEMM_Q=384, halving rule):
//   K=2048 -> 384,384,384,384,256,256 ; K=1024 -> 384,320,320
template <int KSEL>
__device__ inline bool kfold(int kend) {
  if (KSEL == 0)
    return kend == 384 || kend == 768 || kend == 1152 || kend == 1536 || kend == 1792 ||
           kend == 2048;
  return kend == 384 || kend == 704 || kend == 1024;
}

// ============== np-faithful fp32 GEMM: C = op(A)@B + bias ==================
template <int KSEL, bool CLIP>
__global__ __launch_bounds__(256) void gemm_np(const float* __restrict__ A,
                                               const float* __restrict__ B,
                                               const float* __restrict__ bias,
                                               float* __restrict__ C, int M, int N, int K) {
  __shared__ float As[32][68];  // [k][m]
  __shared__ float Bs[32][68];  // [k][n]
  const int tid = threadIdx.x;
  const int tx = tid & 15, ty = tid >> 4;
  const int row0 = blockIdx.y * 64;
  const int col0 = blockIdx.x * 64;
  float cur[4][4], tot[4][4];
#pragma unroll
  for (int i = 0; i < 4; ++i)
#pragma unroll
    for (int j = 0; j < 4; ++j) { cur[i][j] = 0.f; tot[i][j] = 0.f; }

  for (int k0 = 0; k0 < K; k0 += 32) {
#pragma unroll
    for (int l = 0; l < 2; ++l) {
      int s = tid + 256 * l;
      int r = s >> 3;
      int kq = (s & 7) << 2;
      float4 v = *reinterpret_cast<const float4*>(&A[(size_t)(row0 + r) * K + k0 + kq]);
      if (CLIP) { v.x = clip10(v.x); v.y = clip10(v.y); v.z = clip10(v.z); v.w = clip10(v.w); }
      As[kq + 0][r] = v.x; As[kq + 1][r] = v.y; As[kq + 2][r] = v.z; As[kq + 3][r] = v.w;
    }
#pragma unroll
    for (int l = 0; l < 2; ++l) {
      int s = tid + 256 * l;
      int kr = s >> 4;
      int c4 = (s & 15) << 2;
      *reinterpret_cast<float4*>(&Bs[kr][c4]) =
          *reinterpret_cast<const float4*>(&B[(size_t)(k0 + kr) * N + col0 + c4]);
    }
    __syncthreads();
#pragma unroll
    for (int kk = 0; kk < 32; ++kk) {  // k strictly ascending
      float4 a = *reinterpret_cast<const float4*>(&As[kk][ty * 4]);
      float4 b = *reinterpret_cast<const float4*>(&Bs[kk][tx * 4]);
      float da[4] = {a.x, a.y, a.z, a.w};
      float db[4] = {b.x, b.y, b.z, b.w};
#pragma unroll
      for (int i = 0; i < 4; ++i)
#pragma unroll
        for (int j = 0; j < 4; ++j) cur[i][j] = fmaf(da[i], db[j], cur[i][j]);
    }
    __syncthreads();
    if (kfold<KSEL>(k0 + 32)) {
#pragma unroll
      for (int i = 0; i < 4; ++i)
#pragma unroll
        for (int j = 0; j < 4; ++j) { tot[i][j] = __fadd_rn(tot[i][j], cur[i][j]); cur[i][j] = 0.f; }
    }
  }
#pragma unroll
  for (int i = 0; i < 4; ++i) {
    int row = row0 + ty * 4 + i;
#pragma unroll
    for (int j = 0; j < 4; ++j) {
      int col = col0 + tx * 4 + j;
      C[(size_t)row * N + col] = __fadd_rn(tot[i][j], bias[col]);
    }
  }
}

// ===== numpy pairwise row-sum of squares (AVX-512 base-case emulation) ======
__global__ __launch_bounds__(256) void rowsq_np(const float* __restrict__ X, int nrows,
                                                float* __restrict__ out) {
  int row = blockIdx.x * 256 + threadIdx.x;
  if (row >= nrows) return;
  const float* rp = X + (size_t)row * 1024;
  float Bres[8];
#pragma unroll
  for (int blk = 0; blk < 8; ++blk) {
    const float* p = rp + blk * 128;
    float x[16];
#pragma unroll
    for (int L = 0; L < 16; ++L) {
      float m0 = __fmul_rn(p[L], p[L]);
      float m1 = __fmul_rn(p[64 + L], p[64 + L]);
      float r0 = __fadd_rn(m0, m1);
      float m2 = __fmul_rn(p[16 + L], p[16 + L]);
      float m3 = __fmul_rn(p[80 + L], p[80 + L]);
      float r1 = __fadd_rn(m2, m3);
      float m4 = __fmul_rn(p[32 + L], p[32 + L]);
      float m5 = __fmul_rn(p[96 + L], p[96 + L]);
      float r2 = __fadd_rn(m4, m5);
      float m6 = __fmul_rn(p[48 + L], p[48 + L]);
      float m7 = __fmul_rn(p[112 + L], p[112 + L]);
      float r3 = __fadd_rn(m6, m7);
      x[L] = __fadd_rn(__fadd_rn(r0, r1), __fadd_rn(r2, r3));
    }
    float z[4];
#pragma unroll
    for (int i = 0; i < 4; ++i)
      z[i] = __fadd_rn(__fadd_rn(x[i], x[i + 8]), __fadd_rn(x[i + 4], x[i + 12]));
    Bres[blk] = __fadd_rn(__fadd_rn(z[0], z[2]), __fadd_rn(z[1], z[3]));
  }
  float s01 = __fadd_rn(Bres[0], Bres[1]);
  float s23 = __fadd_rn(Bres[2], Bres[3]);
  float s45 = __fadd_rn(Bres[4], Bres[5]);
  float s67 = __fadd_rn(Bres[6], Bres[7]);
  out[row] = __fadd_rn(__fadd_rn(s01, s23), __fadd_rn(s45, s67));
}

// ---------------- fp32 -> fp16 (RNE) with compile-time power-of-2 scale -----
template <int SCALE>
__global__ __launch_bounds__(256) void tofp16_kernel(const float* __restrict__ x,
                                                     _Float16* __restrict__ y, int n4) {
  int i = blockIdx.x * 256 + threadIdx.x;
  if (i >= n4) return;
  float4 v = *reinterpret_cast<const float4*>(x + (size_t)i * 4);
  half4v o;
  o.x = (_Float16)(v.x * (float)SCALE);
  o.y = (_Float16)(v.y * (float)SCALE);
  o.z = (_Float16)(v.z * (float)SCALE);
  o.w = (_Float16)(v.w * (float)SCALE);
  *reinterpret_cast<half4v*>(y + (size_t)i * 4) = o;
}

// ====== fp16 MFMA filter v2: per-(row, 32-code-group) min of scaled score ===
// S'_scaled = -2*(zh . ch) + c2*8192, ch = fp16(c*8192) (exact scale).
// Block: 64 rows x 256 codes, 4 waves in 2x2 (wr: 32-row half, wc: 128-code
// half). Each wave: 2 row-subtiles x 8 code-subtiles = 16 MFMAs per 32-k step
// with 10 LDS fragment reads (round-13's 64x64 tile: 4 MFMAs per 17 reads —
// barrier/LDS-instruction bound). Fragment mapping (m89/m91 HW-verified):
// A row = l&15 (+subtile), k = (l>>4)*8+i; B col = l&15; C/D col = l&15,
// row = (l>>4)*4 + j.
__global__ __launch_bounds__(256, 1) void mfma_filter(const _Float16* __restrict__ zh,
                                                      const _Float16* __restrict__ ch,
                                                      const float* __restrict__ c2,
                                                      _Float16* __restrict__ pv2) {
  __shared__ _Float16 As[64 * 40];    // 5 KB
  __shared__ _Float16 Bs[256 * 40];   // 20 KB
  const int tid = threadIdx.x;
  const int w = tid >> 6, l = tid & 63;
  const int wr = w & 1, wc = w >> 1;
  const int row0 = blockIdx.y * 64;
  const int col0 = blockIdx.x * 256;
  f32x4 acc[2][8];
#pragma unroll
  for (int m = 0; m < 2; ++m)
#pragma unroll
    for (int s = 0; s < 8; ++s) acc[m][s] = (f32x4){0.f, 0.f, 0.f, 0.f};

  for (int kt = 0; kt < DIMV; kt += 32) {
    {  // stage Z: 64 rows x 4 quads (1/thread); C: 256 rows x 4 quads (4/thread)
      int zr = tid >> 2, zq = tid & 3;
      *reinterpret_cast<half8v*>(&As[zr * 40 + zq * 8]) =
          *reinterpret_cast<const half8v*>(&zh[(size_t)(row0 + zr) * DIMV + kt + zq * 8]);
#pragma unroll
      for (int l2 = 0; l2 < 4; ++l2) {
        int s = tid + 256 * l2;
        int cr = s >> 2, cq = s & 3;
        *reinterpret_cast<half8v*>(&Bs[cr * 40 + cq * 8]) =
            *reinterpret_cast<const half8v*>(&ch[(size_t)(col0 + cr) * DIMV + kt + cq * 8]);
      }
    }
    __syncthreads();
    half8v a[2];
#pragma unroll
    for (int m = 0; m < 2; ++m)
      a[m] = *reinterpret_cast<const half8v*>(
          &As[(wr * 32 + m * 16 + (l & 15)) * 40 + (l >> 4) * 8]);
#pragma unroll
    for (int s = 0; s < 8; ++s) {
      half8v b = *reinterpret_cast<const half8v*>(
          &Bs[(wc * 128 + s * 16 + (l & 15)) * 40 + (l >> 4) * 8]);
#pragma unroll
      for (int m = 0; m < 2; ++m)
        acc[m][s] = __builtin_amdgcn_mfma_f32_16x16x32_f16(a[m], b, acc[m][s], 0, 0, 0);
    }
    __syncthreads();
  }
  // acc[m][s][j] = 8192*G(row0+wr*32+m*16+(l>>4)*4+j, col0+wc*128+s*16+(l&15))
  float c2s[8];
#pragma unroll
  for (int s = 0; s < 8; ++s) c2s[s] = c2[col0 + wc * 128 + s * 16 + (l & 15)] * 8192.f;
  float mnp[2][4][4];  // [m][group p][j]
#pragma unroll
  for (int m = 0; m < 2; ++m)
#pragma unroll
    for (int p = 0; p < 4; ++p)
#pragma unroll
      for (int j = 0; j < 4; ++j)
        mnp[m][p][j] = fminf(fmaf(acc[m][2 * p][j], -2.f, c2s[2 * p]),
                             fmaf(acc[m][2 * p + 1][j], -2.f, c2s[2 * p + 1]));
#pragma unroll
  for (int off = 1; off < 16; off <<= 1) {
#pragma unroll
    for (int m = 0; m < 2; ++m)
#pragma unroll
      for (int p = 0; p < 4; ++p)
#pragma unroll
        for (int j = 0; j < 4; ++j)
          mnp[m][p][j] = fminf(mnp[m][p][j], __shfl_xor(mnp[m][p][j], off, 64));
  }
  if ((l & 15) == 0) {
    int q = l >> 4;
#pragma unroll
    for (int m = 0; m < 2; ++m)
#pragma unroll
      for (int p = 0; p < 4; ++p)
#pragma unroll
        for (int j = 0; j < 4; ++j)
          pv2[(size_t)(row0 + wr * 32 + m * 16 + q * 4 + j) * 256 + blockIdx.x * 8 +
              wc * 4 + p] = (_Float16)mnp[m][p][j];
  }
}

// ------ per-row global min of S'_scaled + rigorous error margin -> thr -------
// E <= 2*2^-10*||z||*||c||max + delta_np + slack; ||c||max <= 32/8192 (hard).
// thr_scaled = m + 1.5*(2E)*8192 = m + (sqrt(z2)*2.3e-5 + 4e-5)*8192.
__global__ __launch_bounds__(256) void rowmin_thr(const _Float16* __restrict__ pv2,
                                                  const float* __restrict__ z2,
                                                  float* __restrict__ thr) {
  int row = blockIdx.x * 256 + threadIdx.x;
  const _Float16* pr = pv2 + (size_t)row * 256;
  float m = (float)pr[0];
  for (int g = 1; g < 256; ++g) m = fminf(m, (float)pr[g]);
  thr[row] = m + (sqrtf(z2[row]) * 2.3e-5f + 4.0e-5f) * 8192.f;
}

// ------ exact np-faithful rescore of flagged 32-code groups ------------------
// One wave per row; float4 loads for CB and the LDS z row (k-ascending x,y,z,w
// keeps the fold chain bit-identical; segment bounds 384/704/1024 all %4==0).
__global__ __launch_bounds__(64) void rescore(const _Float16* __restrict__ pv2,
                                              const float* __restrict__ thr,
                                              const float* __restrict__ ze,
                                              const float* __restrict__ CB,
                                              const float* __restrict__ z2,
                                              const float* __restrict__ c2,
                                              float* __restrict__ out_ids,
                                              int* __restrict__ ids,
                                              float* __restrict__ usage) {
  __shared__ float zs[1024];
  int row = blockIdx.x;
  int lane = threadIdx.x;
#pragma unroll
  for (int i = 0; i < 16; ++i) zs[lane + 64 * i] = ze[(size_t)row * DIMV + lane + 64 * i];
  __syncthreads();
  float z2v = z2[row];
  float t = thr[row];
  const _Float16* pr = pv2 + (size_t)row * 256;
  float bestd = FLT_MAX;
  int besti = 0x7fffffff;
  for (int base = 0; base < 256; base += 64) {
    unsigned long long mask = __ballot((float)pr[base + lane] <= t);
    while (mask) {
      int g = __builtin_ctzll(mask);
      mask &= mask - 1;
      int code = (base + g) * 32 + (lane & 31);  // lanes 32-63 duplicate (harmless)
      const float4* cp4 = reinterpret_cast<const float4*>(CB + (size_t)code * DIMV);
      const float4* zs4 = reinterpret_cast<const float4*>(zs);
      float cur = 0.f, tot = 0.f;
#pragma unroll 8
      for (int k4 = 0; k4 < 96; ++k4) {  // k in [0,384)
        float4 c = cp4[k4];
        float4 z = zs4[k4];
        cur = fmaf(z.x, c.x, cur); cur = fmaf(z.y, c.y, cur);
        cur = fmaf(z.z, c.z, cur); cur = fmaf(z.w, c.w, cur);
      }
      tot = __fadd_rn(tot, cur); cur = 0.f;
#pragma unroll 8
      for (int k4 = 96; k4 < 176; ++k4) {  // k in [384,704)
        float4 c = cp4[k4];
        float4 z = zs4[k4];
        cur = fmaf(z.x, c.x, cur); cur = fmaf(z.y, c.y, cur);
        cur = fmaf(z.z, c.z, cur); cur = fmaf(z.w, c.w, cur);
      }
      tot = __fadd_rn(tot, cur); cur = 0.f;
#pragma unroll 8
      for (int k4 = 176; k4 < 256; ++k4) {  // k in [704,1024)
        float4 c = cp4[k4];
        float4 z = zs4[k4];
        cur = fmaf(z.x, c.x, cur); cur = fmaf(z.y, c.y, cur);
        cur = fmaf(z.z, c.z, cur); cur = fmaf(z.w, c.w, cur);
      }
      tot = __fadd_rn(tot, cur);
      float d = __fadd_rn(__fsub_rn(z2v, __fmul_rn(2.f, tot)), c2[code]);
      if (d < bestd || (d == bestd && code < besti)) { bestd = d; besti = code; }
    }
  }
#pragma unroll
  for (int off = 32; off > 0; off >>= 1) {
    float dv = __shfl_xor(bestd, off, 64);
    int iv = __shfl_xor(besti, off, 64);
    if (dv < bestd || (dv == bestd && iv < besti)) { bestd = dv; besti = iv; }
  }
  if (lane == 0) {
    ids[row] = besti;
    out_ids[row] = (float)besti;
    atomicAdd(&usage[besti], 1.0f);  // exact integer-valued floats
  }
}

// ---------------- z_q = codebook[ids] (float32 out) ----------------
__global__ __launch_bounds__(256) void gather_kernel(const int* __restrict__ ids,
                                                     const float* __restrict__ CB,
                                                     float* __restrict__ zq) {
  int row = blockIdx.x;
  int id = ids[row];
  *reinterpret_cast<float4*>(&zq[(size_t)row * DIMV + threadIdx.x * 4]) =
      *reinterpret_cast<const float4*>(&CB[(size_t)id * DIMV + threadIdx.x * 4]);
}

// -------- decoder GEMM 1: h = CB[ids] @ Wd + bd (plain fp32) ---------
__global__ __launch_bounds__(256) void gemm_dec1(const int* __restrict__ ids,
                                                 const float* __restrict__ CB,
                                                 const float* __restrict__ B,
                                                 const float* __restrict__ bias,
                                                 float* __restrict__ C) {
  __shared__ float As[32][68];
  __shared__ float Bs[32][68];
  __shared__ int sid[64];
  const int tid = threadIdx.x;
  const int tx = tid & 15, ty = tid >> 4;
  const int row0 = blockIdx.y * 64;
  const int col0 = blockIdx.x * 64;
  if (tid < 64) sid[tid] = ids[row0 + tid];
  __syncthreads();
  float acc[4][4];
#pragma unroll
  for (int i = 0; i < 4; ++i)
#pragma unroll
    for (int j = 0; j < 4; ++j) acc[i][j] = 0.f;

  for (int k0 = 0; k0 < DIMV; k0 += 32) {
#pragma unroll
    for (int l = 0; l < 2; ++l) {
      int s = tid + 256 * l;
      int r = s >> 3;
      int kq = (s & 7) << 2;
      float4 v = *reinterpret_cast<const float4*>(&CB[(size_t)sid[r] * DIMV + k0 + kq]);
      As[kq + 0][r] = v.x; As[kq + 1][r] = v.y; As[kq + 2][r] = v.z; As[kq + 3][r] = v.w;
    }
#pragma unroll
    for (int l = 0; l < 2; ++l) {
      int s = tid + 256 * l;
      int kr = s >> 4;
      int c4 = (s & 15) << 2;
      *reinterpret_cast<float4*>(&Bs[kr][c4]) =
          *reinterpret_cast<const float4*>(&B[(size_t)(k0 + kr) * DIMV + col0 + c4]);
    }
    __syncthreads();
#pragma unroll
    for (int kk = 0; kk < 32; ++kk) {
      float4 a = *reinterpret_cast<const float4*>(&As[kk][ty * 4]);
      float4 b = *reinterpret_cast<const float4*>(&Bs[kk][tx * 4]);
      float da[4] = {a.x, a.y, a.z, a.w};
      float db[4] = {b.x, b.y, b.z, b.w};
#pragma unroll
      for (int i = 0; i < 4; ++i)
#pragma unroll
        for (int j = 0; j < 4; ++j) acc[i][j] = fmaf(da[i], db[j], acc[i][j]);
    }
    __syncthreads();
  }
#pragma unroll
  for (int i = 0; i < 4; ++i) {
    int row = row0 + ty * 4 + i;
#pragma unroll
    for (int j = 0; j < 4; ++j) {
      int col = col0 + tx * 4 + j;
      C[(size_t)row * DIMV + col] = acc[i][j] + bias[col];
    }
  }
}

// -- decoder GEMM 2: recon = h @ Wo + bo (f32 out) + fused recon-loss partial --
__global__ __launch_bounds__(256) void gemm_dec2(const float* __restrict__ A,
                                                 const float* __restrict__ B,
                                                 const float* __restrict__ bias,
                                                 const float* __restrict__ roi,
                                                 float* __restrict__ Cout,
                                                 float* __restrict__ part) {
  __shared__ float As[32][68];
  __shared__ float Bs[32][68];
  __shared__ float sm[4];
  const int tid = threadIdx.x;
  const int tx = tid & 15, ty = tid >> 4;
  const int row0 = blockIdx.y * 64;
  const int col0 = blockIdx.x * 64;
  float acc[4][4];
#pragma unroll
  for (int i = 0; i < 4; ++i)
#pragma unroll
    for (int j = 0; j < 4; ++j) acc[i][j] = 0.f;

  for (int k0 = 0; k0 < DIMV; k0 += 32) {
#pragma unroll
    for (int l = 0; l < 2; ++l) {
      int s = tid + 256 * l;
      int r = s >> 3;
      int kq = (s & 7) << 2;
      float4 v = *reinterpret_cast<const float4*>(&A[(size_t)(row0 + r) * DIMV + k0 + kq]);
      As[kq + 0][r] = v.x; As[kq + 1][r] = v.y; As[kq + 2][r] = v.z; As[kq + 3][r] = v.w;
    }
#pragma unroll
    for (int l = 0; l < 2; ++l) {
      int s = tid + 256 * l;
      int kr = s >> 4;
      int c4 = (s & 15) << 2;
      *reinterpret_cast<float4*>(&Bs[kr][c4]) =
          *reinterpret_cast<const float4*>(&B[(size_t)(k0 + kr) * INDIM + col0 + c4]);
    }
    __syncthreads();
#pragma unroll
    for (int kk = 0; kk < 32; ++kk) {
      float4 a = *reinterpret_cast<const float4*>(&As[kk][ty * 4]);
      float4 b = *reinterpret_cast<const float4*>(&Bs[kk][tx * 4]);
      float da[4] = {a.x, a.y, a.z, a.w};
      float db[4] = {b.x, b.y, b.z, b.w};
#pragma unroll
      for (int i = 0; i < 4; ++i)
#pragma unroll
        for (int j = 0; j < 4; ++j) acc[i][j] = fmaf(da[i], db[j], acc[i][j]);
    }
    __syncthreads();
  }

  float s = 0.f;
#pragma unroll
  for (int i = 0; i < 4; ++i) {
    int row = row0 + ty * 4 + i;
    int col = col0 + tx * 4;
    float4 x = *reinterpret_cast<const float4*>(&roi[(size_t)row * INDIM + col]);
    float xs[4] = {x.x, x.y, x.z, x.w};
    float vals[4];
#pragma unroll
    for (int j = 0; j < 4; ++j) {
      float val = acc[i][j] + bias[col + j];
      float d = val - clip10(xs[j]);
      s += d * d;
      vals[j] = val;
    }
    *reinterpret_cast<float4*>(&Cout[(size_t)row * INDIM + col]) =
        make_float4(vals[0], vals[1], vals[2], vals[3]);
  }
  float t = block_sum256(s, sm);
  if (tid == 0) part[blockIdx.y * gridDim.x + blockIdx.x] = t;
}

// ---------------- embedding loss partial: sum((CB[id]-ze)^2) per row ---------
__global__ __launch_bounds__(256) void emb_partial(const int* __restrict__ ids,
                                                   const float* __restrict__ CB,
                                                   const float* __restrict__ ze,
                                                   float* __restrict__ part) {
  __shared__ float sm[4];
  int row = blockIdx.x;
  int id = ids[row];
  float4 q = *reinterpret_cast<const float4*>(&CB[(size_t)id * DIMV + threadIdx.x * 4]);
  float4 z = *reinterpret_cast<const float4*>(&ze[(size_t)row * DIMV + threadIdx.x * 4]);
  float dx = q.x - z.x, dy = q.y - z.y, dz = q.z - z.z, dw = q.w - z.w;
  float t = block_sum256(dx * dx + dy * dy + dz * dz + dw * dw, sm);
  if (threadIdx.x == 0) part[row] = t;
}

// ---------------- final reduce: 4 scalar losses ------------------------------
__global__ __launch_bounds__(256) void loss_final(const float* __restrict__ part1,
                                                  const float* __restrict__ part2,
                                                  float* __restrict__ scal) {
  __shared__ float sm[4];
  float s1 = 0.f;
  for (int i = threadIdx.x; i < 8192; i += 256) s1 += part1[i];
  float s2 = 0.f;
  for (int i = threadIdx.x; i < NROWS; i += 256) s2 += part2[i];
  float t1 = block_sum256(s1, sm);
  __syncthreads();
  float t2 = block_sum256(s2, sm);
  if (threadIdx.x == 0) {
    float recon_loss = t1 / 33554432.f;  // N * INDIM
    float emb = t2 / 16777216.f;         // N * DIM
    scal[0] = recon_loss + emb + 0.25f * emb;  // vq = recon + embed + 0.25*commit
    scal[1] = recon_loss;
    scal[2] = emb;
    scal[3] = emb;  // commitment forward value == embedding
  }
}

extern "C" void kernel_launch(void* const* d_in, const int* in_sizes, int n_in,
                              void* d_out, int out_size, void* d_ws, size_t ws_size,
                              hipStream_t stream) {
  const float* roi = (const float*)d_in[0];
  const float* Wp = (const float*)d_in[1];
  const float* bp = (const float*)d_in[2];
  const float* We = (const float*)d_in[3];
  const float* be = (const float*)d_in[4];
  const float* CB = (const float*)d_in[5];
  const float* Wd = (const float*)d_in[6];
  const float* bd = (const float*)d_in[7];
  const float* Wo = (const float*)d_in[8];
  const float* bo = (const float*)d_in[9];

  // float32 output layout: ids[N], z_q[N*DIM], recon[N*INDIM], 4 scalars, usage
  float* out = (float*)d_out;
  float* out_ids = out;
  float* out_zq = out + NROWS;
  float* out_recon = out_zq + (size_t)NROWS * DIMV;
  float* out_scal = out_recon + (size_t)NROWS * INDIM;
  float* out_usage = out_scal + 4;

  // workspace (~137 MB); zh/ch alias z1 (dead between ze and dec1)
  float* ws = (float*)d_ws;
  float* z1 = ws;                                   // N*DIM (reused as h)
  float* ze = z1 + (size_t)NROWS * DIMV;            // N*DIM
  float* z2 = ze + (size_t)NROWS * DIMV;            // N
  float* c2 = z2 + NROWS;                           // NCODE
  int* ids = (int*)(c2 + NCODE);                    // N
  float* part1 = (float*)(ids + NROWS);             // 8192 (recon partials)
  float* part2 = part1 + 8192;                      // N (emb partials)
  _Float16* pv2 = (_Float16*)(part2 + NROWS);       // N*256 fp16 (8.4 MB)
  float* thr = (float*)(pv2 + (size_t)NROWS * 256); // N
  _Float16* zh = (_Float16*)z1;                     // N*DIM fp16 (32 MB, alias)
  _Float16* ch = zh + (size_t)NROWS * DIMV;         // NCODE*DIM fp16 (16 MB, alias)

  zero_kernel<<<32, 256, 0, stream>>>(out_usage, NCODE);  // idempotent per call

  // z1 = clip(roi) @ Wp + bp ; z_e = z1 @ We + be  (np/OpenBLAS-faithful fp32)
  gemm_np<0, true><<<dim3(DIMV / 64, NROWS / 64), 256, 0, stream>>>(roi, Wp, bp, z1, NROWS,
                                                                    DIMV, INDIM);
  gemm_np<1, false><<<dim3(DIMV / 64, NROWS / 64), 256, 0, stream>>>(z1, We, be, ze, NROWS,
                                                                     DIMV, DIMV);
  // z2 = np.sum(z_e*z_e,1), c2 = np.sum(CB*CB,1)  (numpy pairwise emulation)
  rowsq_np<<<NROWS / 256, 256, 0, stream>>>(ze, NROWS, z2);
  rowsq_np<<<NCODE / 256, 256, 0, stream>>>(CB, NCODE, c2);

  // fp16 MFMA filter (c scaled x8192) -> 32-code-group minima -> thr -> rescore
  tofp16_kernel<1><<<NROWS * DIMV / 4 / 256, 256, 0, stream>>>(ze, zh, NROWS * DIMV / 4);
  tofp16_kernel<8192><<<NCODE * DIMV / 4 / 256, 256, 0, stream>>>(CB, ch, NCODE * DIMV / 4);
  mfma_filter<<<dim3(NCODE / 256, NROWS / 64), 256, 0, stream>>>(zh, ch, c2, pv2);
  rowmin_thr<<<NROWS / 256, 256, 0, stream>>>(pv2, z2, thr);
  rescore<<<NROWS, 64, 0, stream>>>(pv2, thr, ze, CB, z2, c2, out_ids, ids, out_usage);

  gather_kernel<<<NROWS, 256, 0, stream>>>(ids, CB, out_zq);

  // decoder: h = CB[ids] @ Wd + bd ; recon = h @ Wo + bo (+ fused recon-loss)
  gemm_dec1<<<dim3(DIMV / 64, NROWS / 64), 256, 0, stream>>>(ids, CB, Wd, bd, z1);
  gemm_dec2<<<dim3(INDIM / 64, NROWS / 64), 256, 0, stream>>>(z1, Wo, bo, roi, out_recon,
                                                              part1);
  // embedding loss partials + final scalars
  emb_partial<<<NROWS, 256, 0, stream>>>(ids, CB, ze, part2);
  loss_final<<<1, 256, 0, stream>>>(part1, part2, out_scal);
}

// Round 15
// 2630.964 us; speedup vs baseline: 7.5024x; 1.7642x over previous
//
#include <hip/hip_runtime.h>
#include <hip/hip_bf16.h>
#include <cfloat>

// Problem constants
#define NROWS 16384
#define INDIM 2048
#define DIMV  1024
#define NCODE 8192

typedef __attribute__((ext_vector_type(8))) _Float16 half8v;
typedef __attribute__((ext_vector_type(4))) _Float16 half4v;
typedef __attribute__((ext_vector_type(4))) float f32x4;

__device__ inline float clip10(float x) { return fminf(fmaxf(x, -10.f), 10.f); }

__device__ inline float block_sum256(float v, float* sm) {
#pragma unroll
  for (int off = 32; off > 0; off >>= 1) v += __shfl_down(v, off, 64);
  int lane = threadIdx.x & 63, w = threadIdx.x >> 6;
  if (lane == 0) sm[w] = v;
  __syncthreads();
  float r = 0.f;
  if (threadIdx.x == 0) r = sm[0] + sm[1] + sm[2] + sm[3];
  return r;  // valid on thread 0 only
}

__global__ void zero_kernel(float* __restrict__ p, int n) {
  int i = blockIdx.x * 256 + threadIdx.x;
  if (i < n) p[i] = 0.f;
}

// OpenBLAS level3 K-panel boundaries (GEMM_Q=384, halving rule):
//   K=2048 -> 384,384,384,384,256,256 ; K=1024 -> 384,320,320
template <int KSEL>
__device__ inline bool kfold(int kend) {
  if (KSEL == 0)
    return kend == 384 || kend == 768 || kend == 1152 || kend == 1536 || kend == 1792 ||
           kend == 2048;
  return kend == 384 || kend == 704 || kend == 1024;
}

// ============== np-faithful fp32 GEMM: C = op(A)@B + bias ==================
template <int KSEL, bool CLIP>
__global__ __launch_bounds__(256) void gemm_np(const float* __restrict__ A,
                                               const float* __restrict__ B,
                                               const float* __restrict__ bias,
                                               float* __restrict__ C, int M, int N, int K) {
  __shared__ float As[32][68];  // [k][m]
  __shared__ float Bs[32][68];  // [k][n]
  const int tid = threadIdx.x;
  const int tx = tid & 15, ty = tid >> 4;
  const int row0 = blockIdx.y * 64;
  const int col0 = blockIdx.x * 64;
  float cur[4][4], tot[4][4];
#pragma unroll
  for (int i = 0; i < 4; ++i)
#pragma unroll
    for (int j = 0; j < 4; ++j) { cur[i][j] = 0.f; tot[i][j] = 0.f; }

  for (int k0 = 0; k0 < K; k0 += 32) {
#pragma unroll
    for (int l = 0; l < 2; ++l) {
      int s = tid + 256 * l;
      int r = s >> 3;
      int kq = (s & 7) << 2;
      float4 v = *reinterpret_cast<const float4*>(&A[(size_t)(row0 + r) * K + k0 + kq]);
      if (CLIP) { v.x = clip10(v.x); v.y = clip10(v.y); v.z = clip10(v.z); v.w = clip10(v.w); }
      As[kq + 0][r] = v.x; As[kq + 1][r] = v.y; As[kq + 2][r] = v.z; As[kq + 3][r] = v.w;
    }
#pragma unroll
    for (int l = 0; l < 2; ++l) {
      int s = tid + 256 * l;
      int kr = s >> 4;
      int c4 = (s & 15) << 2;
      *reinterpret_cast<float4*>(&Bs[kr][c4]) =
          *reinterpret_cast<const float4*>(&B[(size_t)(k0 + kr) * N + col0 + c4]);
    }
    __syncthreads();
#pragma unroll
    for (int kk = 0; kk < 32; ++kk) {  // k strictly ascending
      float4 a = *reinterpret_cast<const float4*>(&As[kk][ty * 4]);
      float4 b = *reinterpret_cast<const float4*>(&Bs[kk][tx * 4]);
      float da[4] = {a.x, a.y, a.z, a.w};
      float db[4] = {b.x, b.y, b.z, b.w};
#pragma unroll
      for (int i = 0; i < 4; ++i)
#pragma unroll
        for (int j = 0; j < 4; ++j) cur[i][j] = fmaf(da[i], db[j], cur[i][j]);
    }
    __syncthreads();
    if (kfold<KSEL>(k0 + 32)) {
#pragma unroll
      for (int i = 0; i < 4; ++i)
#pragma unroll
        for (int j = 0; j < 4; ++j) { tot[i][j] = __fadd_rn(tot[i][j], cur[i][j]); cur[i][j] = 0.f; }
    }
  }
#pragma unroll
  for (int i = 0; i < 4; ++i) {
    int row = row0 + ty * 4 + i;
#pragma unroll
    for (int j = 0; j < 4; ++j) {
      int col = col0 + tx * 4 + j;
      C[(size_t)row * N + col] = __fadd_rn(tot[i][j], bias[col]);
    }
  }
}

// ===== numpy pairwise row-sum of squares (AVX-512 base-case emulation) ======
__global__ __launch_bounds__(256) void rowsq_np(const float* __restrict__ X, int nrows,
                                                float* __restrict__ out) {
  int row = blockIdx.x * 256 + threadIdx.x;
  if (row >= nrows) return;
  const float* rp = X + (size_t)row * 1024;
  float Bres[8];
#pragma unroll
  for (int blk = 0; blk < 8; ++blk) {
    const float* p = rp + blk * 128;
    float x[16];
#pragma unroll
    for (int L = 0; L < 16; ++L) {
      float m0 = __fmul_rn(p[L], p[L]);
      float m1 = __fmul_rn(p[64 + L], p[64 + L]);
      float r0 = __fadd_rn(m0, m1);
      float m2 = __fmul_rn(p[16 + L], p[16 + L]);
      float m3 = __fmul_rn(p[80 + L], p[80 + L]);
      float r1 = __fadd_rn(m2, m3);
      float m4 = __fmul_rn(p[32 + L], p[32 + L]);
      float m5 = __fmul_rn(p[96 + L], p[96 + L]);
      float r2 = __fadd_rn(m4, m5);
      float m6 = __fmul_rn(p[48 + L], p[48 + L]);
      float m7 = __fmul_rn(p[112 + L], p[112 + L]);
      float r3 = __fadd_rn(m6, m7);
      x[L] = __fadd_rn(__fadd_rn(r0, r1), __fadd_rn(r2, r3));
    }
    float z[4];
#pragma unroll
    for (int i = 0; i < 4; ++i)
      z[i] = __fadd_rn(__fadd_rn(x[i], x[i + 8]), __fadd_rn(x[i + 4], x[i + 12]));
    Bres[blk] = __fadd_rn(__fadd_rn(z[0], z[2]), __fadd_rn(z[1], z[3]));
  }
  float s01 = __fadd_rn(Bres[0], Bres[1]);
  float s23 = __fadd_rn(Bres[2], Bres[3]);
  float s45 = __fadd_rn(Bres[4], Bres[5]);
  float s67 = __fadd_rn(Bres[6], Bres[7]);
  out[row] = __fadd_rn(__fadd_rn(s01, s23), __fadd_rn(s45, s67));
}

// ---------------- fp32 -> fp16 (RNE) with compile-time power-of-2 scale -----
template <int SCALE>
__global__ __launch_bounds__(256) void tofp16_kernel(const float* __restrict__ x,
                                                     _Float16* __restrict__ y, int n4) {
  int i = blockIdx.x * 256 + threadIdx.x;
  if (i >= n4) return;
  float4 v = *reinterpret_cast<const float4*>(x + (size_t)i * 4);
  half4v o;
  o.x = (_Float16)(v.x * (float)SCALE);
  o.y = (_Float16)(v.y * (float)SCALE);
  o.z = (_Float16)(v.z * (float)SCALE);
  o.w = (_Float16)(v.w * (float)SCALE);
  *reinterpret_cast<half4v*>(y + (size_t)i * 4) = o;
}

// -------- transpose + fp16 convert: out[c][r] = fp16(in[r][c]) --------------
__global__ __launch_bounds__(256) void transpose_fp16(const float* __restrict__ in,
                                                      _Float16* __restrict__ out, int R,
                                                      int C) {
  __shared__ float t[32][33];
  int bx = blockIdx.x * 32;  // col base
  int by = blockIdx.y * 32;  // row base
  int lx = threadIdx.x & 31, ly = threadIdx.x >> 5;  // 32 x 8
#pragma unroll
  for (int i = 0; i < 32; i += 8)
    t[ly + i][lx] = in[(size_t)(by + ly + i) * C + bx + lx];
  __syncthreads();
#pragma unroll
  for (int i = 0; i < 32; i += 8)
    out[(size_t)(bx + ly + i) * R + by + lx] = (_Float16)t[lx][ly + i];
}

// ====== fp16 MFMA filter: per-(row, 16-code-group) min of scaled score ======
// S'_scaled = -2*(zh . ch) + c2*8192, ch = fp16(c*8192) (exact scale).
// Block: 64 rows x 256 codes, 4 waves 2x2. Fragment mapping (m89/m91 verified):
// A row = l&15 (+subtile), k = (l>>4)*8+i; B col = l&15; C/D col = l&15,
// row = (l>>4)*4 + j. 16-code group == one 16-col subtile s.
__global__ __launch_bounds__(256, 1) void mfma_filter(const _Float16* __restrict__ zh,
                                                      const _Float16* __restrict__ ch,
                                                      const float* __restrict__ c2,
                                                      _Float16* __restrict__ pv2) {
  __shared__ _Float16 As[64 * 40];    // 5 KB
  __shared__ _Float16 Bs[256 * 40];   // 20 KB
  const int tid = threadIdx.x;
  const int w = tid >> 6, l = tid & 63;
  const int wr = w & 1, wc = w >> 1;
  const int row0 = blockIdx.y * 64;
  const int col0 = blockIdx.x * 256;
  f32x4 acc[2][8];
#pragma unroll
  for (int m = 0; m < 2; ++m)
#pragma unroll
    for (int s = 0; s < 8; ++s) acc[m][s] = (f32x4){0.f, 0.f, 0.f, 0.f};

  for (int kt = 0; kt < DIMV; kt += 32) {
    {
      int zr = tid >> 2, zq = tid & 3;
      *reinterpret_cast<half8v*>(&As[zr * 40 + zq * 8]) =
          *reinterpret_cast<const half8v*>(&zh[(size_t)(row0 + zr) * DIMV + kt + zq * 8]);
#pragma unroll
      for (int l2 = 0; l2 < 4; ++l2) {
        int s = tid + 256 * l2;
        int cr = s >> 2, cq = s & 3;
        *reinterpret_cast<half8v*>(&Bs[cr * 40 + cq * 8]) =
            *reinterpret_cast<const half8v*>(&ch[(size_t)(col0 + cr) * DIMV + kt + cq * 8]);
      }
    }
    __syncthreads();
    half8v a[2];
#pragma unroll
    for (int m = 0; m < 2; ++m)
      a[m] = *reinterpret_cast<const half8v*>(
          &As[(wr * 32 + m * 16 + (l & 15)) * 40 + (l >> 4) * 8]);
#pragma unroll
    for (int s = 0; s < 8; ++s) {
      half8v b = *reinterpret_cast<const half8v*>(
          &Bs[(wc * 128 + s * 16 + (l & 15)) * 40 + (l >> 4) * 8]);
#pragma unroll
      for (int m = 0; m < 2; ++m)
        acc[m][s] = __builtin_amdgcn_mfma_f32_16x16x32_f16(a[m], b, acc[m][s], 0, 0, 0);
    }
    __syncthreads();
  }
  // acc[m][s][j] = 8192*G(row0+wr*32+m*16+(l>>4)*4+j, col0+wc*128+s*16+(l&15))
  float c2s[8];
#pragma unroll
  for (int s = 0; s < 8; ++s) c2s[s] = c2[col0 + wc * 128 + s * 16 + (l & 15)] * 8192.f;
  const int q = l >> 4;
#pragma unroll
  for (int m = 0; m < 2; ++m) {
#pragma unroll
    for (int s = 0; s < 8; ++s) {
      float v[4];
#pragma unroll
      for (int j = 0; j < 4; ++j) v[j] = fmaf(acc[m][s][j], -2.f, c2s[s]);
#pragma unroll
      for (int off = 1; off < 16; off <<= 1)
#pragma unroll
        for (int j = 0; j < 4; ++j) v[j] = fminf(v[j], __shfl_xor(v[j], off, 64));
      if ((l & 15) == 0) {
#pragma unroll
        for (int j = 0; j < 4; ++j)
          pv2[(size_t)(row0 + wr * 32 + m * 16 + q * 4 + j) * 512 + blockIdx.x * 16 +
              wc * 8 + s] = (_Float16)v[j];
      }
    }
  }
}

// ------ per-row global min of S'_scaled + rigorous error margin -> thr -------
// E <= 2*2^-10*||z||*||c||max + delta_np + slack; ||c||max <= 32/8192 (hard).
__global__ __launch_bounds__(256) void rowmin_thr(const _Float16* __restrict__ pv2,
                                                  const float* __restrict__ z2,
                                                  float* __restrict__ thr) {
  int row = blockIdx.x * 256 + threadIdx.x;
  const _Float16* pr = pv2 + (size_t)row * 512;
  float m = (float)pr[0];
  for (int g = 1; g < 512; ++g) m = fminf(m, (float)pr[g]);
  thr[row] = m + (sqrtf(z2[row]) * 2.3e-5f + 4.0e-5f) * 8192.f;
}

// ------ exact np-faithful rescore of flagged 16-code groups ------------------
// One wave per row: ballot-compact flagged groups (ascending = np order), then
// 4 groups x 16 codes across 64 lanes per batch; exact fold chain per code
// (k ascending, folds {384,704,1024}, d = fl(fl(z2-2G)+c2)); lex (d,idx) min.
__global__ __launch_bounds__(64) void rescore(const _Float16* __restrict__ pv2,
                                              const float* __restrict__ thr,
                                              const float* __restrict__ ze,
                                              const float* __restrict__ CB,
                                              const float* __restrict__ z2,
                                              const float* __restrict__ c2,
                                              float* __restrict__ out_ids,
                                              int* __restrict__ ids,
                                              float* __restrict__ usage) {
  __shared__ float zs[1024];
  __shared__ int glist[512];
  int row = blockIdx.x;
  int lane = threadIdx.x;
#pragma unroll
  for (int i = 0; i < 16; ++i) zs[lane + 64 * i] = ze[(size_t)row * DIMV + lane + 64 * i];
  float z2v = z2[row];
  float t = thr[row];
  const _Float16* pr = pv2 + (size_t)row * 512;
  int ng = 0;
  for (int base = 0; base < 512; base += 64) {
    bool f = (float)pr[base + lane] <= t;
    unsigned long long mask = __ballot(f);
    if (f) {
      int pos = __popcll(mask & ((1ull << lane) - 1));
      glist[ng + pos] = base + lane;
    }
    ng += __popcll(mask);
  }
  __syncthreads();
  float bestd = FLT_MAX;
  int besti = 0x7fffffff;
  for (int gb = 0; gb < ng; gb += 4) {
    int gi = gb + (lane >> 4);
    float d = FLT_MAX;
    int code = 0x7fffffff;
    if (gi < ng) {
      code = glist[gi] * 16 + (lane & 15);
      const float4* cp4 = reinterpret_cast<const float4*>(CB + (size_t)code * DIMV);
      const float4* zs4 = reinterpret_cast<const float4*>(zs);
      float cur = 0.f, tot = 0.f;
#pragma unroll 8
      for (int k4 = 0; k4 < 96; ++k4) {  // k in [0,384)
        float4 c = cp4[k4];
        float4 z = zs4[k4];
        cur = fmaf(z.x, c.x, cur); cur = fmaf(z.y, c.y, cur);
        cur = fmaf(z.z, c.z, cur); cur = fmaf(z.w, c.w, cur);
      }
      tot = __fadd_rn(tot, cur); cur = 0.f;
#pragma unroll 8
      for (int k4 = 96; k4 < 176; ++k4) {  // k in [384,704)
        float4 c = cp4[k4];
        float4 z = zs4[k4];
        cur = fmaf(z.x, c.x, cur); cur = fmaf(z.y, c.y, cur);
        cur = fmaf(z.z, c.z, cur); cur = fmaf(z.w, c.w, cur);
      }
      tot = __fadd_rn(tot, cur); cur = 0.f;
#pragma unroll 8
      for (int k4 = 176; k4 < 256; ++k4) {  // k in [704,1024)
        float4 c = cp4[k4];
        float4 z = zs4[k4];
        cur = fmaf(z.x, c.x, cur); cur = fmaf(z.y, c.y, cur);
        cur = fmaf(z.z, c.z, cur); cur = fmaf(z.w, c.w, cur);
      }
      tot = __fadd_rn(tot, cur);
      d = __fadd_rn(__fsub_rn(z2v, __fmul_rn(2.f, tot)), c2[code]);
    }
    if (d < bestd || (d == bestd && code < besti)) { bestd = d; besti = code; }
  }
#pragma unroll
  for (int off = 32; off > 0; off >>= 1) {
    float dv = __shfl_xor(bestd, off, 64);
    int iv = __shfl_xor(besti, off, 64);
    if (dv < bestd || (dv == bestd && iv < besti)) { bestd = dv; besti = iv; }
  }
  if (lane == 0) {
    ids[row] = besti;
    out_ids[row] = (float)besti;
    atomicAdd(&usage[besti], 1.0f);  // exact integer-valued floats
  }
}

// ---------------- z_q = codebook[ids] (float32 out) ----------------
__global__ __launch_bounds__(256) void gather_kernel(const int* __restrict__ ids,
                                                     const float* __restrict__ CB,
                                                     float* __restrict__ zq) {
  int row = blockIdx.x;
  int id = ids[row];
  *reinterpret_cast<float4*>(&zq[(size_t)row * DIMV + threadIdx.x * 4]) =
      *reinterpret_cast<const float4*>(&CB[(size_t)id * DIMV + threadIdx.x * 4]);
}

// ====== decoder GEMM 1 (fp16 MFMA): h = z_q @ Wd + bd, h stored x1024 =======
// A = ch[ids[row]] (fp16 CB x8192); B = WdT [col][k] fp16. acc = 8192*(zq@Wd).
// h_store = fp16(acc/8 + 1024*bd)  (= 1024*h; exact pow2 scales).
// 2% rel threshold downstream: fp16 input rounding (2^-11) -> ~0.03% error.
__global__ __launch_bounds__(256, 1) void dec1_mfma(const int* __restrict__ ids,
                                                    const _Float16* __restrict__ ch,
                                                    const _Float16* __restrict__ WdT,
                                                    const float* __restrict__ bd,
                                                    _Float16* __restrict__ h) {
  __shared__ _Float16 As[64 * 40];
  __shared__ _Float16 Bs[256 * 40];
  __shared__ int sid[64];
  const int tid = threadIdx.x;
  const int w = tid >> 6, l = tid & 63;
  const int wr = w & 1, wc = w >> 1;
  const int row0 = blockIdx.y * 64;
  const int col0 = blockIdx.x * 256;
  if (tid < 64) sid[tid] = ids[row0 + tid];
  __syncthreads();
  f32x4 acc[2][8];
#pragma unroll
  for (int m = 0; m < 2; ++m)
#pragma unroll
    for (int s = 0; s < 8; ++s) acc[m][s] = (f32x4){0.f, 0.f, 0.f, 0.f};

  for (int kt = 0; kt < DIMV; kt += 32) {
    {
      int zr = tid >> 2, zq = tid & 3;
      *reinterpret_cast<half8v*>(&As[zr * 40 + zq * 8]) =
          *reinterpret_cast<const half8v*>(&ch[(size_t)sid[zr] * DIMV + kt + zq * 8]);
#pragma unroll
      for (int l2 = 0; l2 < 4; ++l2) {
        int s = tid + 256 * l2;
        int cr = s >> 2, cq = s & 3;
        *reinterpret_cast<half8v*>(&Bs[cr * 40 + cq * 8]) =
            *reinterpret_cast<const half8v*>(&WdT[(size_t)(col0 + cr) * DIMV + kt + cq * 8]);
      }
    }
    __syncthreads();
    half8v a[2];
#pragma unroll
    for (int m = 0; m < 2; ++m)
      a[m] = *reinterpret_cast<const half8v*>(
          &As[(wr * 32 + m * 16 + (l & 15)) * 40 + (l >> 4) * 8]);
#pragma unroll
    for (int s = 0; s < 8; ++s) {
      half8v b = *reinterpret_cast<const half8v*>(
          &Bs[(wc * 128 + s * 16 + (l & 15)) * 40 + (l >> 4) * 8]);
#pragma unroll
      for (int m = 0; m < 2; ++m)
        acc[m][s] = __builtin_amdgcn_mfma_f32_16x16x32_f16(a[m], b, acc[m][s], 0, 0, 0);
    }
    __syncthreads();
  }
  const int q = l >> 4;
#pragma unroll
  for (int m = 0; m < 2; ++m)
#pragma unroll
    for (int s = 0; s < 8; ++s) {
      int col = col0 + wc * 128 + s * 16 + (l & 15);
#pragma unroll
      for (int j = 0; j < 4; ++j) {
        int row = row0 + wr * 32 + m * 16 + q * 4 + j;
        h[(size_t)row * DIMV + col] =
            (_Float16)(acc[m][s][j] * 0.125f + 1024.f * bd[col]);
      }
    }
}

// == decoder GEMM 2 (fp16 MFMA): recon = h @ Wo + bo (f32) + fused loss ======
// A = h (x1024 fp16); B = WoT [col][k] fp16. recon = acc/1024 + bo.
__global__ __launch_bounds__(256, 1) void dec2_mfma(const _Float16* __restrict__ h,
                                                    const _Float16* __restrict__ WoT,
                                                    const float* __restrict__ bo,
                                                    const float* __restrict__ roi,
                                                    float* __restrict__ recon,
                                                    float* __restrict__ part) {
  __shared__ _Float16 As[64 * 40];
  __shared__ _Float16 Bs[256 * 40];
  __shared__ float sm[4];
  const int tid = threadIdx.x;
  const int w = tid >> 6, l = tid & 63;
  const int wr = w & 1, wc = w >> 1;
  const int row0 = blockIdx.y * 64;
  const int col0 = blockIdx.x * 256;
  f32x4 acc[2][8];
#pragma unroll
  for (int m = 0; m < 2; ++m)
#pragma unroll
    for (int s = 0; s < 8; ++s) acc[m][s] = (f32x4){0.f, 0.f, 0.f, 0.f};

  for (int kt = 0; kt < DIMV; kt += 32) {
    {
      int zr = tid >> 2, zq = tid & 3;
      *reinterpret_cast<half8v*>(&As[zr * 40 + zq * 8]) =
          *reinterpret_cast<const half8v*>(&h[(size_t)(row0 + zr) * DIMV + kt + zq * 8]);
#pragma unroll
      for (int l2 = 0; l2 < 4; ++l2) {
        int s = tid + 256 * l2;
        int cr = s >> 2, cq = s & 3;
        *reinterpret_cast<half8v*>(&Bs[cr * 40 + cq * 8]) =
            *reinterpret_cast<const half8v*>(&WoT[(size_t)(col0 + cr) * DIMV + kt + cq * 8]);
      }
    }
    __syncthreads();
    half8v a[2];
#pragma unroll
    for (int m = 0; m < 2; ++m)
      a[m] = *reinterpret_cast<const half8v*>(
          &As[(wr * 32 + m * 16 + (l & 15)) * 40 + (l >> 4) * 8]);
#pragma unroll
    for (int s = 0; s < 8; ++s) {
      half8v b = *reinterpret_cast<const half8v*>(
          &Bs[(wc * 128 + s * 16 + (l & 15)) * 40 + (l >> 4) * 8]);
#pragma unroll
      for (int m = 0; m < 2; ++m)
        acc[m][s] = __builtin_amdgcn_mfma_f32_16x16x32_f16(a[m], b, acc[m][s], 0, 0, 0);
    }
    __syncthreads();
  }
  const int q = l >> 4;
  float se = 0.f;
#pragma unroll
  for (int m = 0; m < 2; ++m)
#pragma unroll
    for (int s = 0; s < 8; ++s) {
      int col = col0 + wc * 128 + s * 16 + (l & 15);
#pragma unroll
      for (int j = 0; j < 4; ++j) {
        int row = row0 + wr * 32 + m * 16 + q * 4 + j;
        float val = acc[m][s][j] * (1.f / 1024.f) + bo[col];
        float d = val - clip10(roi[(size_t)row * INDIM + col]);
        se += d * d;
        recon[(size_t)row * INDIM + col] = val;
      }
    }
  float tt = block_sum256(se, sm);
  if (tid == 0) part[blockIdx.y * gridDim.x + blockIdx.x] = tt;
}

// ---------------- embedding loss partial: sum((CB[id]-ze)^2) per row ---------
__global__ __launch_bounds__(256) void emb_partial(const int* __restrict__ ids,
                                                   const float* __restrict__ CB,
                                                   const float* __restrict__ ze,
                                                   float* __restrict__ part) {
  __shared__ float sm[4];
  int row = blockIdx.x;
  int id = ids[row];
  float4 q = *reinterpret_cast<const float4*>(&CB[(size_t)id * DIMV + threadIdx.x * 4]);
  float4 z = *reinterpret_cast<const float4*>(&ze[(size_t)row * DIMV + threadIdx.x * 4]);
  float dx = q.x - z.x, dy = q.y - z.y, dz = q.z - z.z, dw = q.w - z.w;
  float t = block_sum256(dx * dx + dy * dy + dz * dz + dw * dw, sm);
  if (threadIdx.x == 0) part[row] = t;
}

// ---------------- final reduce: 4 scalar losses ------------------------------
__global__ __launch_bounds__(256) void loss_final(const float* __restrict__ part1,
                                                  const float* __restrict__ part2,
                                                  float* __restrict__ scal) {
  __shared__ float sm[4];
  float s1 = 0.f;
  for (int i = threadIdx.x; i < 2048; i += 256) s1 += part1[i];
  float s2 = 0.f;
  for (int i = threadIdx.x; i < NROWS; i += 256) s2 += part2[i];
  float t1 = block_sum256(s1, sm);
  __syncthreads();
  float t2 = block_sum256(s2, sm);
  if (threadIdx.x == 0) {
    float recon_loss = t1 / 33554432.f;  // N * INDIM
    float emb = t2 / 16777216.f;         // N * DIM
    scal[0] = recon_loss + emb + 0.25f * emb;  // vq = recon + embed + 0.25*commit
    scal[1] = recon_loss;
    scal[2] = emb;
    scal[3] = emb;  // commitment forward value == embedding
  }
}

extern "C" void kernel_launch(void* const* d_in, const int* in_sizes, int n_in,
                              void* d_out, int out_size, void* d_ws, size_t ws_size,
                              hipStream_t stream) {
  const float* roi = (const float*)d_in[0];
  const float* Wp = (const float*)d_in[1];
  const float* bp = (const float*)d_in[2];
  const float* We = (const float*)d_in[3];
  const float* be = (const float*)d_in[4];
  const float* CB = (const float*)d_in[5];
  const float* Wd = (const float*)d_in[6];
  const float* bd = (const float*)d_in[7];
  const float* Wo = (const float*)d_in[8];
  const float* bo = (const float*)d_in[9];

  // float32 output layout: ids[N], z_q[N*DIM], recon[N*INDIM], 4 scalars, usage
  float* out = (float*)d_out;
  float* out_ids = out;
  float* out_zq = out + NROWS;
  float* out_recon = out_zq + (size_t)NROWS * DIMV;
  float* out_scal = out_recon + (size_t)NROWS * INDIM;
  float* out_usage = out_scal + 4;

  // workspace (~151 MB); zh/ch/h alias z1 (zh dead after mfma_filter)
  float* ws = (float*)d_ws;
  float* z1 = ws;                                   // N*DIM fp32 (64 MB)
  float* ze = z1 + (size_t)NROWS * DIMV;            // N*DIM
  float* z2 = ze + (size_t)NROWS * DIMV;            // N
  float* c2 = z2 + NROWS;                           // NCODE
  int* ids = (int*)(c2 + NCODE);                    // N
  float* part1 = (float*)(ids + NROWS);             // 2048 (recon partials)
  float* part2 = part1 + 2048;                      // N (emb partials)
  _Float16* pv2 = (_Float16*)(part2 + NROWS);       // N*512 fp16 (16 MB)
  float* thr = (float*)(pv2 + (size_t)NROWS * 512); // N
  _Float16* WdT = (_Float16*)(thr + NROWS);         // 1024*1024 fp16 (2 MB)
  _Float16* WoT = WdT + (size_t)DIMV * DIMV;        // 2048*1024 fp16 (4 MB)
  _Float16* zh = (_Float16*)z1;                     // N*DIM fp16 (alias)
  _Float16* ch = zh + (size_t)NROWS * DIMV;         // NCODE*DIM fp16 (alias)
  _Float16* hbuf = (_Float16*)z1;                   // N*DIM fp16 (alias, post-rescore)

  zero_kernel<<<32, 256, 0, stream>>>(out_usage, NCODE);  // idempotent per call

  // z1 = clip(roi) @ Wp + bp ; z_e = z1 @ We + be  (np/OpenBLAS-faithful fp32)
  gemm_np<0, true><<<dim3(DIMV / 64, NROWS / 64), 256, 0, stream>>>(roi, Wp, bp, z1, NROWS,
                                                                    DIMV, INDIM);
  gemm_np<1, false><<<dim3(DIMV / 64, NROWS / 64), 256, 0, stream>>>(z1, We, be, ze, NROWS,
                                                                     DIMV, DIMV);
  // z2 = np.sum(z_e*z_e,1), c2 = np.sum(CB*CB,1)  (numpy pairwise emulation)
  rowsq_np<<<NROWS / 256, 256, 0, stream>>>(ze, NROWS, z2);
  rowsq_np<<<NCODE / 256, 256, 0, stream>>>(CB, NCODE, c2);

  // fp16 conversions + W transposes for the MFMA kernels
  tofp16_kernel<1><<<NROWS * DIMV / 4 / 256, 256, 0, stream>>>(ze, zh, NROWS * DIMV / 4);
  tofp16_kernel<8192><<<NCODE * DIMV / 4 / 256, 256, 0, stream>>>(CB, ch, NCODE * DIMV / 4);
  transpose_fp16<<<dim3(DIMV / 32, DIMV / 32), 256, 0, stream>>>(Wd, WdT, DIMV, DIMV);
  transpose_fp16<<<dim3(INDIM / 32, DIMV / 32), 256, 0, stream>>>(Wo, WoT, DIMV, INDIM);

  // fp16 MFMA filter -> 16-code-group minima -> threshold -> exact np rescore
  mfma_filter<<<dim3(NCODE / 256, NROWS / 64), 256, 0, stream>>>(zh, ch, c2, pv2);
  rowmin_thr<<<NROWS / 256, 256, 0, stream>>>(pv2, z2, thr);
  rescore<<<NROWS, 64, 0, stream>>>(pv2, thr, ze, CB, z2, c2, out_ids, ids, out_usage);

  gather_kernel<<<NROWS, 256, 0, stream>>>(ids, CB, out_zq);

  // decoder (fp16 MFMA): h = z_q @ Wd + bd ; recon = h @ Wo + bo (+ loss)
  dec1_mfma<<<dim3(DIMV / 256, NROWS / 64), 256, 0, stream>>>(ids, ch, WdT, bd, hbuf);
  dec2_mfma<<<dim3(INDIM / 256, NROWS / 64), 256, 0, stream>>>(hbuf, WoT, bo, roi,
                                                               out_recon, part1);
  // embedding loss partials + final scalars
  emb_partial<<<NROWS, 256, 0, stream>>>(ids, CB, ze, part2);
  loss_final<<<1, 256, 0, stream>>>(part1, part2, out_scal);
}

// Round 16
// 2572.576 us; speedup vs baseline: 7.6727x; 1.0227x over previous
//
#include <hip/hip_runtime.h>
#include <hip/hip_bf16.h>
#include <cfloat>

// Problem constants
#define NROWS 16384
#define INDIM 2048
#define DIMV  1024
#define NCODE 8192

typedef __attribute__((ext_vector_type(8))) _Float16 half8v;
typedef __attribute__((ext_vector_type(4))) _Float16 half4v;
typedef __attribute__((ext_vector_type(4))) float f32x4;

__device__ inline float clip10(float x) { return fminf(fmaxf(x, -10.f), 10.f); }

__device__ inline float block_sum256(float v, float* sm) {
#pragma unroll
  for (int off = 32; off > 0; off >>= 1) v += __shfl_down(v, off, 64);
  int lane = threadIdx.x & 63, w = threadIdx.x >> 6;
  if (lane == 0) sm[w] = v;
  __syncthreads();
  float r = 0.f;
  if (threadIdx.x == 0) r = sm[0] + sm[1] + sm[2] + sm[3];
  return r;  // valid on thread 0 only
}

__global__ void zero_kernel(float* __restrict__ p, int n) {
  int i = blockIdx.x * 256 + threadIdx.x;
  if (i < n) p[i] = 0.f;
}

// OpenBLAS level3 K-panel boundaries (GEMM_Q=384, halving rule):
//   K=2048 -> 384,384,384,384,256,256 ; K=1024 -> 384,320,320
template <int KSEL>
__device__ inline bool kfold(int kend) {
  if (KSEL == 0)
    return kend == 384 || kend == 768 || kend == 1152 || kend == 1536 || kend == 1792 ||
           kend == 2048;
  return kend == 384 || kend == 704 || kend == 1024;
}

// ============== np-faithful fp32 GEMM: C = op(A)@B + bias ==================
// Per-output chain: sequential-k fmaf, register folds at OpenBLAS K panels —
// BIT-IDENTICAL to the round-5..15 passing kernels (tiling doesn't touch it).
// v2 tile: 128 rows x 64 cols per block, BK=32, 256 threads, 8x4 per thread
// (4x4 was only 16 FMAs per LDS-read pair; 8x4 doubles FMA per overhead op).
// cur+tot = 64 acc regs -> fits (256,2), no spill (round-9 precedent, 92 VGPR).
template <int KSEL, bool CLIP>
__global__ __launch_bounds__(256, 2) void gemm_np(const float* __restrict__ A,
                                                  const float* __restrict__ B,
                                                  const float* __restrict__ bias,
                                                  float* __restrict__ C, int M, int N,
                                                  int K) {
  __shared__ float As[32][132];  // [k][m], 128 rows
  __shared__ float Bs[32][68];   // [k][n], 64 cols
  const int tid = threadIdx.x;
  const int tx = tid & 15, ty = tid >> 4;
  const int row0 = blockIdx.y * 128;
  const int col0 = blockIdx.x * 64;
  float cur[8][4], tot[8][4];
#pragma unroll
  for (int i = 0; i < 8; ++i)
#pragma unroll
    for (int j = 0; j < 4; ++j) { cur[i][j] = 0.f; tot[i][j] = 0.f; }

  for (int k0 = 0; k0 < K; k0 += 32) {
#pragma unroll
    for (int l = 0; l < 4; ++l) {  // A: 128 rows x 8 quads = 1024 quads, 4/thread
      int s = tid + 256 * l;
      int r = s >> 3;
      int kq = (s & 7) << 2;
      float4 v = *reinterpret_cast<const float4*>(&A[(size_t)(row0 + r) * K + k0 + kq]);
      if (CLIP) { v.x = clip10(v.x); v.y = clip10(v.y); v.z = clip10(v.z); v.w = clip10(v.w); }
      As[kq + 0][r] = v.x; As[kq + 1][r] = v.y; As[kq + 2][r] = v.z; As[kq + 3][r] = v.w;
    }
#pragma unroll
    for (int l = 0; l < 2; ++l) {  // B: 32 k x 16 col-quads = 512 quads, 2/thread
      int s = tid + 256 * l;
      int kr = s >> 4;
      int c4 = (s & 15) << 2;
      *reinterpret_cast<float4*>(&Bs[kr][c4]) =
          *reinterpret_cast<const float4*>(&B[(size_t)(k0 + kr) * N + col0 + c4]);
    }
    __syncthreads();
#pragma unroll
    for (int kk = 0; kk < 32; ++kk) {  // k strictly ascending
      float4 a0 = *reinterpret_cast<const float4*>(&As[kk][ty * 8]);
      float4 a1 = *reinterpret_cast<const float4*>(&As[kk][ty * 8 + 4]);
      float4 b = *reinterpret_cast<const float4*>(&Bs[kk][tx * 4]);
      float da[8] = {a0.x, a0.y, a0.z, a0.w, a1.x, a1.y, a1.z, a1.w};
      float db[4] = {b.x, b.y, b.z, b.w};
#pragma unroll
      for (int i = 0; i < 8; ++i)
#pragma unroll
        for (int j = 0; j < 4; ++j) cur[i][j] = fmaf(da[i], db[j], cur[i][j]);
    }
    __syncthreads();
    if (kfold<KSEL>(k0 + 32)) {
#pragma unroll
      for (int i = 0; i < 8; ++i)
#pragma unroll
        for (int j = 0; j < 4; ++j) { tot[i][j] = __fadd_rn(tot[i][j], cur[i][j]); cur[i][j] = 0.f; }
    }
  }
#pragma unroll
  for (int i = 0; i < 8; ++i) {
    int row = row0 + ty * 8 + i;
#pragma unroll
    for (int j = 0; j < 4; ++j) {
      int col = col0 + tx * 4 + j;
      C[(size_t)row * N + col] = __fadd_rn(tot[i][j], bias[col]);
    }
  }
}

// ===== numpy pairwise row-sum of squares (AVX-512 base-case emulation) ======
__global__ __launch_bounds__(256) void rowsq_np(const float* __restrict__ X, int nrows,
                                                float* __restrict__ out) {
  int row = blockIdx.x * 256 + threadIdx.x;
  if (row >= nrows) return;
  const float* rp = X + (size_t)row * 1024;
  float Bres[8];
#pragma unroll
  for (int blk = 0; blk < 8; ++blk) {
    const float* p = rp + blk * 128;
    float x[16];
#pragma unroll
    for (int L = 0; L < 16; ++L) {
      float m0 = __fmul_rn(p[L], p[L]);
      float m1 = __fmul_rn(p[64 + L], p[64 + L]);
      float r0 = __fadd_rn(m0, m1);
      float m2 = __fmul_rn(p[16 + L], p[16 + L]);
      float m3 = __fmul_rn(p[80 + L], p[80 + L]);
      float r1 = __fadd_rn(m2, m3);
      float m4 = __fmul_rn(p[32 + L], p[32 + L]);
      float m5 = __fmul_rn(p[96 + L], p[96 + L]);
      float r2 = __fadd_rn(m4, m5);
      float m6 = __fmul_rn(p[48 + L], p[48 + L]);
      float m7 = __fmul_rn(p[112 + L], p[112 + L]);
      float r3 = __fadd_rn(m6, m7);
      x[L] = __fadd_rn(__fadd_rn(r0, r1), __fadd_rn(r2, r3));
    }
    float z[4];
#pragma unroll
    for (int i = 0; i < 4; ++i)
      z[i] = __fadd_rn(__fadd_rn(x[i], x[i + 8]), __fadd_rn(x[i + 4], x[i + 12]));
    Bres[blk] = __fadd_rn(__fadd_rn(z[0], z[2]), __fadd_rn(z[1], z[3]));
  }
  float s01 = __fadd_rn(Bres[0], Bres[1]);
  float s23 = __fadd_rn(Bres[2], Bres[3]);
  float s45 = __fadd_rn(Bres[4], Bres[5]);
  float s67 = __fadd_rn(Bres[6], Bres[7]);
  out[row] = __fadd_rn(__fadd_rn(s01, s23), __fadd_rn(s45, s67));
}

// ---------------- fp32 -> fp16 (RNE) with compile-time power-of-2 scale -----
template <int SCALE>
__global__ __launch_bounds__(256) void tofp16_kernel(const float* __restrict__ x,
                                                     _Float16* __restrict__ y, int n4) {
  int i = blockIdx.x * 256 + threadIdx.x;
  if (i >= n4) return;
  float4 v = *reinterpret_cast<const float4*>(x + (size_t)i * 4);
  half4v o;
  o.x = (_Float16)(v.x * (float)SCALE);
  o.y = (_Float16)(v.y * (float)SCALE);
  o.z = (_Float16)(v.z * (float)SCALE);
  o.w = (_Float16)(v.w * (float)SCALE);
  *reinterpret_cast<half4v*>(y + (size_t)i * 4) = o;
}

// -------- transpose + fp16 convert: out[c][r] = fp16(in[r][c]) --------------
__global__ __launch_bounds__(256) void transpose_fp16(const float* __restrict__ in,
                                                      _Float16* __restrict__ out, int R,
                                                      int C) {
  __shared__ float t[32][33];
  int bx = blockIdx.x * 32;  // col base
  int by = blockIdx.y * 32;  // row base
  int lx = threadIdx.x & 31, ly = threadIdx.x >> 5;  // 32 x 8
#pragma unroll
  for (int i = 0; i < 32; i += 8)
    t[ly + i][lx] = in[(size_t)(by + ly + i) * C + bx + lx];
  __syncthreads();
#pragma unroll
  for (int i = 0; i < 32; i += 8)
    out[(size_t)(bx + ly + i) * R + by + lx] = (_Float16)t[lx][ly + i];
}

// ====== fp16 MFMA filter: per-(row, 16-code-group) min of scaled score ======
// S'_scaled = -2*(zh . ch) + c2*8192, ch = fp16(c*8192) (exact scale).
// Block: 64 rows x 256 codes, 4 waves 2x2. Fragment mapping (m89/m91 verified):
// A row = l&15 (+subtile), k = (l>>4)*8+i; B col = l&15; C/D col = l&15,
// row = (l>>4)*4 + j. 16-code group == one 16-col subtile s.
__global__ __launch_bounds__(256, 1) void mfma_filter(const _Float16* __restrict__ zh,
                                                      const _Float16* __restrict__ ch,
                                                      const float* __restrict__ c2,
                                                      _Float16* __restrict__ pv2) {
  __shared__ _Float16 As[64 * 40];    // 5 KB
  __shared__ _Float16 Bs[256 * 40];   // 20 KB
  const int tid = threadIdx.x;
  const int w = tid >> 6, l = tid & 63;
  const int wr = w & 1, wc = w >> 1;
  const int row0 = blockIdx.y * 64;
  const int col0 = blockIdx.x * 256;
  f32x4 acc[2][8];
#pragma unroll
  for (int m = 0; m < 2; ++m)
#pragma unroll
    for (int s = 0; s < 8; ++s) acc[m][s] = (f32x4){0.f, 0.f, 0.f, 0.f};

  for (int kt = 0; kt < DIMV; kt += 32) {
    {
      int zr = tid >> 2, zq = tid & 3;
      *reinterpret_cast<half8v*>(&As[zr * 40 + zq * 8]) =
          *reinterpret_cast<const half8v*>(&zh[(size_t)(row0 + zr) * DIMV + kt + zq * 8]);
#pragma unroll
      for (int l2 = 0; l2 < 4; ++l2) {
        int s = tid + 256 * l2;
        int cr = s >> 2, cq = s & 3;
        *reinterpret_cast<half8v*>(&Bs[cr * 40 + cq * 8]) =
            *reinterpret_cast<const half8v*>(&ch[(size_t)(col0 + cr) * DIMV + kt + cq * 8]);
      }
    }
    __syncthreads();
    half8v a[2];
#pragma unroll
    for (int m = 0; m < 2; ++m)
      a[m] = *reinterpret_cast<const half8v*>(
          &As[(wr * 32 + m * 16 + (l & 15)) * 40 + (l >> 4) * 8]);
#pragma unroll
    for (int s = 0; s < 8; ++s) {
      half8v b = *reinterpret_cast<const half8v*>(
          &Bs[(wc * 128 + s * 16 + (l & 15)) * 40 + (l >> 4) * 8]);
#pragma unroll
      for (int m = 0; m < 2; ++m)
        acc[m][s] = __builtin_amdgcn_mfma_f32_16x16x32_f16(a[m], b, acc[m][s], 0, 0, 0);
    }
    __syncthreads();
  }
  // acc[m][s][j] = 8192*G(row0+wr*32+m*16+(l>>4)*4+j, col0+wc*128+s*16+(l&15))
  float c2s[8];
#pragma unroll
  for (int s = 0; s < 8; ++s) c2s[s] = c2[col0 + wc * 128 + s * 16 + (l & 15)] * 8192.f;
  const int q = l >> 4;
#pragma unroll
  for (int m = 0; m < 2; ++m) {
#pragma unroll
    for (int s = 0; s < 8; ++s) {
      float v[4];
#pragma unroll
      for (int j = 0; j < 4; ++j) v[j] = fmaf(acc[m][s][j], -2.f, c2s[s]);
#pragma unroll
      for (int off = 1; off < 16; off <<= 1)
#pragma unroll
        for (int j = 0; j < 4; ++j) v[j] = fminf(v[j], __shfl_xor(v[j], off, 64));
      if ((l & 15) == 0) {
#pragma unroll
        for (int j = 0; j < 4; ++j)
          pv2[(size_t)(row0 + wr * 32 + m * 16 + q * 4 + j) * 512 + blockIdx.x * 16 +
              wc * 8 + s] = (_Float16)v[j];
      }
    }
  }
}

// ------ per-row global min of S'_scaled + rigorous error margin -> thr -------
// E <= 2*2^-10*||z||*||c||max + delta_np + slack; ||c||max <= 32/8192 (hard).
__global__ __launch_bounds__(256) void rowmin_thr(const _Float16* __restrict__ pv2,
                                                  const float* __restrict__ z2,
                                                  float* __restrict__ thr) {
  int row = blockIdx.x * 256 + threadIdx.x;
  const _Float16* pr = pv2 + (size_t)row * 512;
  float m = (float)pr[0];
  for (int g = 1; g < 512; ++g) m = fminf(m, (float)pr[g]);
  thr[row] = m + (sqrtf(z2[row]) * 2.3e-5f + 4.0e-5f) * 8192.f;
}

// ------ exact np-faithful rescore of flagged 16-code groups ------------------
// One wave per row: ballot-compact flagged groups (ascending = np order), then
// 4 groups x 16 codes across 64 lanes per batch; exact fold chain per code
// (k ascending, folds {384,704,1024}, d = fl(fl(z2-2G)+c2)); lex (d,idx) min.
__global__ __launch_bounds__(64) void rescore(const _Float16* __restrict__ pv2,
                                              const float* __restrict__ thr,
                                              const float* __restrict__ ze,
                                              const float* __restrict__ CB,
                                              const float* __restrict__ z2,
                                              const float* __restrict__ c2,
                                              float* __restrict__ out_ids,
                                              int* __restrict__ ids,
                                              float* __restrict__ usage) {
  __shared__ float zs[1024];
  __shared__ int glist[512];
  int row = blockIdx.x;
  int lane = threadIdx.x;
#pragma unroll
  for (int i = 0; i < 16; ++i) zs[lane + 64 * i] = ze[(size_t)row * DIMV + lane + 64 * i];
  float z2v = z2[row];
  float t = thr[row];
  const _Float16* pr = pv2 + (size_t)row * 512;
  int ng = 0;
  for (int base = 0; base < 512; base += 64) {
    bool f = (float)pr[base + lane] <= t;
    unsigned long long mask = __ballot(f);
    if (f) {
      int pos = __popcll(mask & ((1ull << lane) - 1));
      glist[ng + pos] = base + lane;
    }
    ng += __popcll(mask);
  }
  __syncthreads();
  float bestd = FLT_MAX;
  int besti = 0x7fffffff;
  for (int gb = 0; gb < ng; gb += 4) {
    int gi = gb + (lane >> 4);
    float d = FLT_MAX;
    int code = 0x7fffffff;
    if (gi < ng) {
      code = glist[gi] * 16 + (lane & 15);
      const float4* cp4 = reinterpret_cast<const float4*>(CB + (size_t)code * DIMV);
      const float4* zs4 = reinterpret_cast<const float4*>(zs);
      float cur = 0.f, tot = 0.f;
#pragma unroll 8
      for (int k4 = 0; k4 < 96; ++k4) {  // k in [0,384)
        float4 c = cp4[k4];
        float4 z = zs4[k4];
        cur = fmaf(z.x, c.x, cur); cur = fmaf(z.y, c.y, cur);
        cur = fmaf(z.z, c.z, cur); cur = fmaf(z.w, c.w, cur);
      }
      tot = __fadd_rn(tot, cur); cur = 0.f;
#pragma unroll 8
      for (int k4 = 96; k4 < 176; ++k4) {  // k in [384,704)
        float4 c = cp4[k4];
        float4 z = zs4[k4];
        cur = fmaf(z.x, c.x, cur); cur = fmaf(z.y, c.y, cur);
        cur = fmaf(z.z, c.z, cur); cur = fmaf(z.w, c.w, cur);
      }
      tot = __fadd_rn(tot, cur); cur = 0.f;
#pragma unroll 8
      for (int k4 = 176; k4 < 256; ++k4) {  // k in [704,1024)
        float4 c = cp4[k4];
        float4 z = zs4[k4];
        cur = fmaf(z.x, c.x, cur); cur = fmaf(z.y, c.y, cur);
        cur = fmaf(z.z, c.z, cur); cur = fmaf(z.w, c.w, cur);
      }
      tot = __fadd_rn(tot, cur);
      d = __fadd_rn(__fsub_rn(z2v, __fmul_rn(2.f, tot)), c2[code]);
    }
    if (d < bestd || (d == bestd && code < besti)) { bestd = d; besti = code; }
  }
#pragma unroll
  for (int off = 32; off > 0; off >>= 1) {
    float dv = __shfl_xor(bestd, off, 64);
    int iv = __shfl_xor(besti, off, 64);
    if (dv < bestd || (dv == bestd && iv < besti)) { bestd = dv; besti = iv; }
  }
  if (lane == 0) {
    ids[row] = besti;
    out_ids[row] = (float)besti;
    atomicAdd(&usage[besti], 1.0f);  // exact integer-valued floats
  }
}

// ---------------- z_q = codebook[ids] (float32 out) ----------------
__global__ __launch_bounds__(256) void gather_kernel(const int* __restrict__ ids,
                                                     const float* __restrict__ CB,
                                                     float* __restrict__ zq) {
  int row = blockIdx.x;
  int id = ids[row];
  *reinterpret_cast<float4*>(&zq[(size_t)row * DIMV + threadIdx.x * 4]) =
      *reinterpret_cast<const float4*>(&CB[(size_t)id * DIMV + threadIdx.x * 4]);
}

// ====== decoder GEMM 1 (fp16 MFMA): h = z_q @ Wd + bd, h stored x1024 =======
// A = ch[ids[row]] (fp16 CB x8192); B = WdT [col][k] fp16. acc = 8192*(zq@Wd).
// h_store = fp16(acc/8 + 1024*bd)  (= 1024*h; exact pow2 scales).
__global__ __launch_bounds__(256, 1) void dec1_mfma(const int* __restrict__ ids,
                                                    const _Float16* __restrict__ ch,
                                                    const _Float16* __restrict__ WdT,
                                                    const float* __restrict__ bd,
                                                    _Float16* __restrict__ h) {
  __shared__ _Float16 As[64 * 40];
  __shared__ _Float16 Bs[256 * 40];
  __shared__ int sid[64];
  const int tid = threadIdx.x;
  const int w = tid >> 6, l = tid & 63;
  const int wr = w & 1, wc = w >> 1;
  const int row0 = blockIdx.y * 64;
  const int col0 = blockIdx.x * 256;
  if (tid < 64) sid[tid] = ids[row0 + tid];
  __syncthreads();
  f32x4 acc[2][8];
#pragma unroll
  for (int m = 0; m < 2; ++m)
#pragma unroll
    for (int s = 0; s < 8; ++s) acc[m][s] = (f32x4){0.f, 0.f, 0.f, 0.f};

  for (int kt = 0; kt < DIMV; kt += 32) {
    {
      int zr = tid >> 2, zq = tid & 3;
      *reinterpret_cast<half8v*>(&As[zr * 40 + zq * 8]) =
          *reinterpret_cast<const half8v*>(&ch[(size_t)sid[zr] * DIMV + kt + zq * 8]);
#pragma unroll
      for (int l2 = 0; l2 < 4; ++l2) {
        int s = tid + 256 * l2;
        int cr = s >> 2, cq = s & 3;
        *reinterpret_cast<half8v*>(&Bs[cr * 40 + cq * 8]) =
            *reinterpret_cast<const half8v*>(&WdT[(size_t)(col0 + cr) * DIMV + kt + cq * 8]);
      }
    }
    __syncthreads();
    half8v a[2];
#pragma unroll
    for (int m = 0; m < 2; ++m)
      a[m] = *reinterpret_cast<const half8v*>(
          &As[(wr * 32 + m * 16 + (l & 15)) * 40 + (l >> 4) * 8]);
#pragma unroll
    for (int s = 0; s < 8; ++s) {
      half8v b = *reinterpret_cast<const half8v*>(
          &Bs[(wc * 128 + s * 16 + (l & 15)) * 40 + (l >> 4) * 8]);
#pragma unroll
      for (int m = 0; m < 2; ++m)
        acc[m][s] = __builtin_amdgcn_mfma_f32_16x16x32_f16(a[m], b, acc[m][s], 0, 0, 0);
    }
    __syncthreads();
  }
  const int q = l >> 4;
#pragma unroll
  for (int m = 0; m < 2; ++m)
#pragma unroll
    for (int s = 0; s < 8; ++s) {
      int col = col0 + wc * 128 + s * 16 + (l & 15);
#pragma unroll
      for (int j = 0; j < 4; ++j) {
        int row = row0 + wr * 32 + m * 16 + q * 4 + j;
        h[(size_t)row * DIMV + col] =
            (_Float16)(acc[m][s][j] * 0.125f + 1024.f * bd[col]);
      }
    }
}

// == decoder GEMM 2 (fp16 MFMA): recon = h @ Wo + bo (f32) + fused loss ======
__global__ __launch_bounds__(256, 1) void dec2_mfma(const _Float16* __restrict__ h,
                                                    const _Float16* __restrict__ WoT,
                                                    const float* __restrict__ bo,
                                                    const float* __restrict__ roi,
                                                    float* __restrict__ recon,
                                                    float* __restrict__ part) {
  __shared__ _Float16 As[64 * 40];
  __shared__ _Float16 Bs[256 * 40];
  __shared__ float sm[4];
  const int tid = threadIdx.x;
  const int w = tid >> 6, l = tid & 63;
  const int wr = w & 1, wc = w >> 1;
  const int row0 = blockIdx.y * 64;
  const int col0 = blockIdx.x * 256;
  f32x4 acc[2][8];
#pragma unroll
  for (int m = 0; m < 2; ++m)
#pragma unroll
    for (int s = 0; s < 8; ++s) acc[m][s] = (f32x4){0.f, 0.f, 0.f, 0.f};

  for (int kt = 0; kt < DIMV; kt += 32) {
    {
      int zr = tid >> 2, zq = tid & 3;
      *reinterpret_cast<half8v*>(&As[zr * 40 + zq * 8]) =
          *reinterpret_cast<const half8v*>(&h[(size_t)(row0 + zr) * DIMV + kt + zq * 8]);
#pragma unroll
      for (int l2 = 0; l2 < 4; ++l2) {
        int s = tid + 256 * l2;
        int cr = s >> 2, cq = s & 3;
        *reinterpret_cast<half8v*>(&Bs[cr * 40 + cq * 8]) =
            *reinterpret_cast<const half8v*>(&WoT[(size_t)(col0 + cr) * DIMV + kt + cq * 8]);
      }
    }
    __syncthreads();
    half8v a[2];
#pragma unroll
    for (int m = 0; m < 2; ++m)
      a[m] = *reinterpret_cast<const half8v*>(
          &As[(wr * 32 + m * 16 + (l & 15)) * 40 + (l >> 4) * 8]);
#pragma unroll
    for (int s = 0; s < 8; ++s) {
      half8v b = *reinterpret_cast<const half8v*>(
          &Bs[(wc * 128 + s * 16 + (l & 15)) * 40 + (l >> 4) * 8]);
#pragma unroll
      for (int m = 0; m < 2; ++m)
        acc[m][s] = __builtin_amdgcn_mfma_f32_16x16x32_f16(a[m], b, acc[m][s], 0, 0, 0);
    }
    __syncthreads();
  }
  const int q = l >> 4;
  float se = 0.f;
#pragma unroll
  for (int m = 0; m < 2; ++m)
#pragma unroll
    for (int s = 0; s < 8; ++s) {
      int col = col0 + wc * 128 + s * 16 + (l & 15);
#pragma unroll
      for (int j = 0; j < 4; ++j) {
        int row = row0 + wr * 32 + m * 16 + q * 4 + j;
        float val = acc[m][s][j] * (1.f / 1024.f) + bo[col];
        float d = val - clip10(roi[(size_t)row * INDIM + col]);
        se += d * d;
        recon[(size_t)row * INDIM + col] = val;
      }
    }
  float tt = block_sum256(se, sm);
  if (tid == 0) part[blockIdx.y * gridDim.x + blockIdx.x] = tt;
}

// ---------------- embedding loss partial: sum((CB[id]-ze)^2) per row ---------
__global__ __launch_bounds__(256) void emb_partial(const int* __restrict__ ids,
                                                   const float* __restrict__ CB,
                                                   const float* __restrict__ ze,
                                                   float* __restrict__ part) {
  __shared__ float sm[4];
  int row = blockIdx.x;
  int id = ids[row];
  float4 q = *reinterpret_cast<const float4*>(&CB[(size_t)id * DIMV + threadIdx.x * 4]);
  float4 z = *reinterpret_cast<const float4*>(&ze[(size_t)row * DIMV + threadIdx.x * 4]);
  float dx = q.x - z.x, dy = q.y - z.y, dz = q.z - z.z, dw = q.w - z.w;
  float t = block_sum256(dx * dx + dy * dy + dz * dz + dw * dw, sm);
  if (threadIdx.x == 0) part[row] = t;
}

// ---------------- final reduce: 4 scalar losses ------------------------------
__global__ __launch_bounds__(256) void loss_final(const float* __restrict__ part1,
                                                  const float* __restrict__ part2,
                                                  float* __restrict__ scal) {
  __shared__ float sm[4];
  float s1 = 0.f;
  for (int i = threadIdx.x; i < 2048; i += 256) s1 += part1[i];
  float s2 = 0.f;
  for (int i = threadIdx.x; i < NROWS; i += 256) s2 += part2[i];
  float t1 = block_sum256(s1, sm);
  __syncthreads();
  float t2 = block_sum256(s2, sm);
  if (threadIdx.x == 0) {
    float recon_loss = t1 / 33554432.f;  // N * INDIM
    float emb = t2 / 16777216.f;         // N * DIM
    scal[0] = recon_loss + emb + 0.25f * emb;  // vq = recon + embed + 0.25*commit
    scal[1] = recon_loss;
    scal[2] = emb;
    scal[3] = emb;  // commitment forward value == embedding
  }
}

extern "C" void kernel_launch(void* const* d_in, const int* in_sizes, int n_in,
                              void* d_out, int out_size, void* d_ws, size_t ws_size,
                              hipStream_t stream) {
  const float* roi = (const float*)d_in[0];
  const float* Wp = (const float*)d_in[1];
  const float* bp = (const float*)d_in[2];
  const float* We = (const float*)d_in[3];
  const float* be = (const float*)d_in[4];
  const float* CB = (const float*)d_in[5];
  const float* Wd = (const float*)d_in[6];
  const float* bd = (const float*)d_in[7];
  const float* Wo = (const float*)d_in[8];
  const float* bo = (const float*)d_in[9];

  // float32 output layout: ids[N], z_q[N*DIM], recon[N*INDIM], 4 scalars, usage
  float* out = (float*)d_out;
  float* out_ids = out;
  float* out_zq = out + NROWS;
  float* out_recon = out_zq + (size_t)NROWS * DIMV;
  float* out_scal = out_recon + (size_t)NROWS * INDIM;
  float* out_usage = out_scal + 4;

  // workspace (~151 MB); zh/ch/h alias z1 (zh dead after mfma_filter)
  float* ws = (float*)d_ws;
  float* z1 = ws;                                   // N*DIM fp32 (64 MB)
  float* ze = z1 + (size_t)NROWS * DIMV;            // N*DIM
  float* z2 = ze + (size_t)NROWS * DIMV;            // N
  float* c2 = z2 + NROWS;                           // NCODE
  int* ids = (int*)(c2 + NCODE);                    // N
  float* part1 = (float*)(ids + NROWS);             // 2048 (recon partials)
  float* part2 = part1 + 2048;                      // N (emb partials)
  _Float16* pv2 = (_Float16*)(part2 + NROWS);       // N*512 fp16 (16 MB)
  float* thr = (float*)(pv2 + (size_t)NROWS * 512); // N
  _Float16* WdT = (_Float16*)(thr + NROWS);         // 1024*1024 fp16 (2 MB)
  _Float16* WoT = WdT + (size_t)DIMV * DIMV;        // 2048*1024 fp16 (4 MB)
  _Float16* zh = (_Float16*)z1;                     // N*DIM fp16 (alias)
  _Float16* ch = zh + (size_t)NROWS * DIMV;         // NCODE*DIM fp16 (alias)
  _Float16* hbuf = (_Float16*)z1;                   // N*DIM fp16 (alias, post-rescore)

  zero_kernel<<<32, 256, 0, stream>>>(out_usage, NCODE);  // idempotent per call

  // z1 = clip(roi) @ Wp + bp ; z_e = z1 @ We + be  (np/OpenBLAS-faithful fp32)
  gemm_np<0, true><<<dim3(DIMV / 64, NROWS / 128), 256, 0, stream>>>(roi, Wp, bp, z1, NROWS,
                                                                     DIMV, INDIM);
  gemm_np<1, false><<<dim3(DIMV / 64, NROWS / 128), 256, 0, stream>>>(z1, We, be, ze, NROWS,
                                                                      DIMV, DIMV);
  // z2 = np.sum(z_e*z_e,1), c2 = np.sum(CB*CB,1)  (numpy pairwise emulation)
  rowsq_np<<<NROWS / 256, 256, 0, stream>>>(ze, NROWS, z2);
  rowsq_np<<<NCODE / 256, 256, 0, stream>>>(CB, NCODE, c2);

  // fp16 conversions + W transposes for the MFMA kernels
  tofp16_kernel<1><<<NROWS * DIMV / 4 / 256, 256, 0, stream>>>(ze, zh, NROWS * DIMV / 4);
  tofp16_kernel<8192><<<NCODE * DIMV / 4 / 256, 256, 0, stream>>>(CB, ch, NCODE * DIMV / 4);
  transpose_fp16<<<dim3(DIMV / 32, DIMV / 32), 256, 0, stream>>>(Wd, WdT, DIMV, DIMV);
  transpose_fp16<<<dim3(INDIM / 32, DIMV / 32), 256, 0, stream>>>(Wo, WoT, DIMV, INDIM);

  // fp16 MFMA filter -> 16-code-group minima -> threshold -> exact np rescore
  mfma_filter<<<dim3(NCODE / 256, NROWS / 64), 256, 0, stream>>>(zh, ch, c2, pv2);
  rowmin_thr<<<NROWS / 256, 256, 0, stream>>>(pv2, z2, thr);
  rescore<<<NROWS, 64, 0, stream>>>(pv2, thr, ze, CB, z2, c2, out_ids, ids, out_usage);

  gather_kernel<<<NROWS, 256, 0, stream>>>(ids, CB, out_zq);

  // decoder (fp16 MFMA): h = z_q @ Wd + bd ; recon = h @ Wo + bo (+ loss)
  dec1_mfma<<<dim3(DIMV / 256, NROWS / 64), 256, 0, stream>>>(ids, ch, WdT, bd, hbuf);
  dec2_mfma<<<dim3(INDIM / 256, NROWS / 64), 256, 0, stream>>>(hbuf, WoT, bo, roi,
                                                               out_recon, part1);
  // embedding loss partials + final scalars
  emb_partial<<<NROWS, 256, 0, stream>>>(ids, CB, ze, part2);
  loss_final<<<1, 256, 0, stream>>>(part1, part2, out_scal);
}